// Round 1
// baseline (423.878 us; speedup 1.0000x reference)
//
#include <hip/hip_runtime.h>
#include <hip/hip_bf16.h>
#include <stdint.h>

typedef float f32x4 __attribute__((ext_vector_type(4)));
typedef short s16x8 __attribute__((ext_vector_type(8)));
typedef unsigned short u16x2 __attribute__((ext_vector_type(2)));
typedef unsigned short u16x4 __attribute__((ext_vector_type(4)));

#define AS1 __attribute__((address_space(1)))
#define AS3 __attribute__((address_space(3)))

static constexpr int T_    = 2048;
static constexpr int DIM_  = 3072;
static constexpr int HQ_   = 32;
static constexpr int HKV_  = 8;
static constexpr int HD_   = 128;
static constexpr int S_    = 4096;
static constexpr int NQKV_ = HQ_ * HD_ + 2 * HKV_ * HD_;   // 6144

__device__ __forceinline__ unsigned short f2b(float f) {
  return __builtin_bit_cast(unsigned short, __float2bfloat16(f));
}
__device__ __forceinline__ float b2f(unsigned short u) {
  return __bfloat162float(__builtin_bit_cast(__hip_bfloat16, u));
}

__device__ __forceinline__ void gld_lds16(const void* g, void* l) {
  __builtin_amdgcn_global_load_lds((AS1 unsigned int*)(uintptr_t)g,
                                   (AS3 unsigned int*)l, 16, 0, 0);
}

// ---------------- f32 -> bf16 convert ----------------
__global__ __launch_bounds__(256)
void k_cvt(const float* __restrict__ src, unsigned short* __restrict__ dst, int n4) {
  int i = blockIdx.x * 256 + threadIdx.x;
  if (i >= n4) return;
  float4 v = reinterpret_cast<const float4*>(src)[i];
  u16x4 o;
  o.x = f2b(v.x); o.y = f2b(v.y); o.z = f2b(v.z); o.w = f2b(v.w);
  reinterpret_cast<u16x4*>(dst)[i] = o;
}

// ---------------- NT GEMM: C[M][N] = A[M][K] * B[N][K]^T (bf16 in, f32 acc) --
// m97 structure: 128x128 tile, BK=64, global_load_lds width 16, 4 waves 2x2.
template<bool OUT_BF16>
__global__ __launch_bounds__(256)
void k_gemm_nt(const unsigned short* __restrict__ A,
               const unsigned short* __restrict__ B,
               void* __restrict__ Cout, int M, int N, int K) {
  constexpr int BM = 128, BN = 128, BK = 64;
  __shared__ unsigned short As[BM * BK];
  __shared__ unsigned short Bs[BN * BK];
  const int nbn  = N / BN;
  const int bm   = blockIdx.x / nbn;
  const int bn   = blockIdx.x % nbn;
  const int tid  = threadIdx.x;
  const int lane = tid & 63;
  const int wave = tid >> 6;
  const int r16  = lane & 15, q4 = lane >> 4;
  const int wm   = (wave >> 1) * 64, wn = (wave & 1) * 64;

  f32x4 acc[4][4] = {};

  for (int kt = 0; kt < K; kt += BK) {
    __syncthreads();                       // prior compute done reading LDS
    #pragma unroll
    for (int p = 0; p < 4; ++p) {
      int e   = p * 256 + tid;             // 0..1023
      int row = e >> 3;                    // 0..127
      int col = (e & 7) << 3;              // 0..56
      gld_lds16(A + (size_t)(bm * BM + row) * K + kt + col, As + e * 8);
      gld_lds16(B + (size_t)(bn * BN + row) * K + kt + col, Bs + e * 8);
    }
    __syncthreads();                       // staging complete (vmcnt drained)
    #pragma unroll
    for (int kk = 0; kk < 2; ++kk) {
      s16x8 af[4], bfr[4];
      #pragma unroll
      for (int i = 0; i < 4; ++i)
        af[i] = *reinterpret_cast<const s16x8*>(As + (wm + i * 16 + r16) * BK + kk * 32 + q4 * 8);
      #pragma unroll
      for (int j = 0; j < 4; ++j)
        bfr[j] = *reinterpret_cast<const s16x8*>(Bs + (wn + j * 16 + r16) * BK + kk * 32 + q4 * 8);
      #pragma unroll
      for (int i = 0; i < 4; ++i)
        #pragma unroll
        for (int j = 0; j < 4; ++j)
          acc[i][j] = __builtin_amdgcn_mfma_f32_16x16x32_bf16(af[i], bfr[j], acc[i][j], 0, 0, 0);
    }
  }
  const int rbase = bm * BM + wm + q4 * 4;
  const int cbase = bn * BN + wn + r16;
  if constexpr (OUT_BF16) {
    unsigned short* C = (unsigned short*)Cout;
    #pragma unroll
    for (int i = 0; i < 4; ++i)
      #pragma unroll
      for (int j = 0; j < 4; ++j)
        #pragma unroll
        for (int r = 0; r < 4; ++r)
          C[(size_t)(rbase + i * 16 + r) * N + cbase + j * 16] = f2b(acc[i][j][r]);
  } else {
    float* C = (float*)Cout;
    #pragma unroll
    for (int i = 0; i < 4; ++i)
      #pragma unroll
      for (int j = 0; j < 4; ++j)
        #pragma unroll
        for (int r = 0; r < 4; ++r)
          C[(size_t)(rbase + i * 16 + r) * N + cbase + j * 16] = acc[i][j][r];
  }
}

// ---------------- RoPE on Q: qkv[t][h*128+d] -> Qr[h][t][d] ----------------
__global__ __launch_bounds__(256)
void k_rope_q(const unsigned short* __restrict__ qkv,
              const float* __restrict__ fc, const float* __restrict__ fs,
              unsigned short* __restrict__ Qr) {
  int idx = blockIdx.x * 256 + threadIdx.x;   // T*HQ*64
  int t   = idx >> 11;
  int rem = idx & 2047;
  int h   = rem >> 6;
  int d0  = (rem & 63) << 1;
  size_t qoff = (size_t)t * NQKV_ + h * HD_ + d0;
  u16x2 xv = *reinterpret_cast<const u16x2*>(&qkv[qoff]);
  float x0 = b2f(xv.x), x1 = b2f(xv.y);
  float c0 = fc[t * HD_ + d0], c1 = fc[t * HD_ + d0 + 1];
  float s0 = fs[t * HD_ + d0], s1 = fs[t * HD_ + d0 + 1];
  u16x2 o;
  o.x = f2b(x0 * c0 - x1 * s0);
  o.y = f2b(x1 * c1 + x0 * s1);
  *reinterpret_cast<u16x2*>(&Qr[((size_t)h * T_ + t) * HD_ + d0]) = o;
}

// ---------------- RoPE on K + scatter into Kall[hk][sp+t][d] ---------------
__global__ __launch_bounds__(256)
void k_rope_k(const unsigned short* __restrict__ qkv,
              const float* __restrict__ fc, const float* __restrict__ fs,
              unsigned short* __restrict__ Kall, const int* __restrict__ ipos) {
  int idx = blockIdx.x * 256 + threadIdx.x;   // T*HKV*64
  int t   = idx >> 9;
  int rem = idx & 511;
  int hk  = rem >> 6;
  int d0  = (rem & 63) << 1;
  int sp  = ipos[0];
  size_t qoff = (size_t)t * NQKV_ + HQ_ * HD_ + hk * HD_ + d0;
  u16x2 xv = *reinterpret_cast<const u16x2*>(&qkv[qoff]);
  float x0 = b2f(xv.x), x1 = b2f(xv.y);
  float c0 = fc[t * HD_ + d0], c1 = fc[t * HD_ + d0 + 1];
  float s0 = fs[t * HD_ + d0], s1 = fs[t * HD_ + d0 + 1];
  unsigned short o0 = f2b(x0 * c0 - x1 * s0);
  unsigned short o1 = f2b(x1 * c1 + x0 * s1);
  size_t ooff = ((size_t)hk * S_ + sp + t) * HD_ + d0;
  Kall[ooff] = o0; Kall[ooff + 1] = o1;
}

// ---------------- cache prefix (s < sp) into Kall / VT ---------------------
__global__ __launch_bounds__(256)
void k_prefix(const float* __restrict__ kc, const float* __restrict__ vc,
              unsigned short* __restrict__ Kall, unsigned short* __restrict__ VT,
              const int* __restrict__ ipos) {
  int idx = blockIdx.x * 256 + threadIdx.x;   // S*HKV*HD
  int s   = idx >> 10;
  int sp  = ipos[0];
  if (s >= sp) return;
  int rem = idx & 1023;
  int hk  = rem >> 7;
  int d   = rem & 127;
  Kall[((size_t)hk * S_ + s) * HD_ + d] = f2b(kc[((size_t)s * HKV_ + hk) * HD_ + d]);
  VT[((size_t)hk * HD_ + d) * S_ + s]   = f2b(vc[((size_t)s * HKV_ + hk) * HD_ + d]);
}

// ---------------- V transpose: qkv v-section -> VT[hk][d][sp+t] ------------
__global__ __launch_bounds__(256)
void k_vt(const unsigned short* __restrict__ qkv,
          unsigned short* __restrict__ VT, const int* __restrict__ ipos) {
  int hk = blockIdx.x >> 5;     // 0..7
  int tt = blockIdx.x & 31;     // 0..31 (tiles of 64 t)
  int sp = ipos[0];
  __shared__ unsigned short lds[64][136];
  int tid = threadIdx.x;
  #pragma unroll
  for (int p = 0; p < 4; ++p) {
    int e   = p * 256 + tid;            // 0..1023
    int tr  = e >> 4;                   // 0..63
    int col = (e & 15) << 3;            // 0..120
    *reinterpret_cast<s16x8*>(&lds[tr][col]) =
        *reinterpret_cast<const s16x8*>(&qkv[(size_t)(tt * 64 + tr) * NQKV_ + (HQ_ + HKV_) * HD_ + hk * HD_ + col]);
  }
  __syncthreads();
  #pragma unroll
  for (int p = 0; p < 32; ++p) {
    int e = p * 256 + tid;              // 0..8191
    int d = e >> 6;                     // 0..127
    int t = e & 63;
    VT[((size_t)hk * HD_ + d) * S_ + sp + tt * 64 + t] = lds[t][d];
  }
}

// ---------------- flash attention (GQA, causal) ----------------------------
// grid (HQ, T/64); 4 waves x 16 q-rows; KVBLK=64; padded LDS.
__global__ __launch_bounds__(256)
void k_attn(const unsigned short* __restrict__ Qr,
            const unsigned short* __restrict__ Kall,
            const unsigned short* __restrict__ VT,
            unsigned short* __restrict__ Y,
            const int* __restrict__ ipos) {
  constexpr int QB = 64, KB = 64;
  const int h    = blockIdx.x;
  const int qt   = blockIdx.y;
  const int hk   = h >> 2;
  const int sp   = ipos[0];
  const int tid  = threadIdx.x, lane = tid & 63, wave = tid >> 6;
  const int r16  = lane & 15, q4 = lane >> 4;
  const float NEG_INF = -__builtin_inff();

  __shared__ unsigned short Ks[KB][HD_ + 8];      // 64 x 136
  __shared__ unsigned short Vs[HD_][KB + 8];      // 128 x 72
  __shared__ unsigned short Ps[4][16][KB + 8];    // per-wave 16 x 72

  // Q fragments in registers (rows: qt*64 + wave*16 + r16)
  const int qrow = qt * QB + wave * 16 + r16;
  s16x8 qf[4];
  const unsigned short* qp = Qr + ((size_t)h * T_ + qrow) * HD_;
  #pragma unroll
  for (int ki = 0; ki < 4; ++ki)
    qf[ki] = *reinterpret_cast<const s16x8*>(qp + ki * 32 + q4 * 8);

  f32x4 o[8] = {};
  float m[4], l[4];
  #pragma unroll
  for (int r = 0; r < 4; ++r) { m[r] = NEG_INF; l[r] = 0.f; }

  const int qpos_wave_max = sp + qt * QB + wave * 16 + 15;
  int jmax = (sp + qt * QB + QB - 1) >> 6;
  if (jmax > S_ / KB - 1) jmax = S_ / KB - 1;
  const float scale = 0.08838834764831845f;

  const unsigned short* Kbase = Kall + (size_t)hk * S_ * HD_;
  const unsigned short* Vbase = VT + (size_t)hk * HD_ * S_;

  for (int j = 0; j <= jmax; ++j) {
    // register-staged loads (issued before barrier: overlaps prior compute)
    s16x8 kreg[4], vreg[4];
    #pragma unroll
    for (int p = 0; p < 4; ++p) {
      int e  = p * 256 + tid;
      int kr = e >> 4, kc = (e & 15) << 3;
      kreg[p] = *reinterpret_cast<const s16x8*>(Kbase + (size_t)(j * KB + kr) * HD_ + kc);
      int vd = e >> 3, vs = (e & 7) << 3;
      vreg[p] = *reinterpret_cast<const s16x8*>(Vbase + (size_t)vd * S_ + j * KB + vs);
    }
    __syncthreads();
    #pragma unroll
    for (int p = 0; p < 4; ++p) {
      int e  = p * 256 + tid;
      int kr = e >> 4, kc = (e & 15) << 3;
      *reinterpret_cast<s16x8*>(&Ks[kr][kc]) = kreg[p];
      int vd = e >> 3, vs = (e & 7) << 3;
      *reinterpret_cast<s16x8*>(&Vs[vd][vs]) = vreg[p];
    }
    __syncthreads();

    const bool active = (j * KB <= qpos_wave_max);
    if (active) {
      // S = Q K^T  (NT; both operands row-major-K)
      f32x4 sfr[4];
      #pragma unroll
      for (int fn = 0; fn < 4; ++fn) {
        sfr[fn] = f32x4{0.f, 0.f, 0.f, 0.f};
        #pragma unroll
        for (int ki = 0; ki < 4; ++ki) {
          s16x8 kf = *reinterpret_cast<const s16x8*>(&Ks[fn * 16 + r16][ki * 32 + q4 * 8]);
          sfr[fn] = __builtin_amdgcn_mfma_f32_16x16x32_bf16(qf[ki], kf, sfr[fn], 0, 0, 0);
        }
      }
      // scale + causal mask + online softmax
      float pv[4][4];
      float mnew[4];
      #pragma unroll
      for (int r = 0; r < 4; ++r) mnew[r] = m[r];
      #pragma unroll
      for (int fn = 0; fn < 4; ++fn) {
        int kpos = j * KB + fn * 16 + r16;
        #pragma unroll
        for (int r = 0; r < 4; ++r) {
          int qpos = sp + qt * QB + wave * 16 + q4 * 4 + r;
          float s = sfr[fn][r] * scale;
          s = (kpos <= qpos) ? s : NEG_INF;
          pv[fn][r] = s;
          mnew[r] = fmaxf(mnew[r], s);
        }
      }
      #pragma unroll
      for (int r = 0; r < 4; ++r)
        #pragma unroll
        for (int d = 1; d < 16; d <<= 1)
          mnew[r] = fmaxf(mnew[r], __shfl_xor(mnew[r], d));
      float alpha[4], rsum[4];
      #pragma unroll
      for (int r = 0; r < 4; ++r) {
        alpha[r] = (mnew[r] == NEG_INF) ? 1.0f : __expf(m[r] - mnew[r]);
        m[r] = mnew[r];
        l[r] *= alpha[r];
        float srow = 0.f;
        #pragma unroll
        for (int fn = 0; fn < 4; ++fn) {
          float p = (pv[fn][r] == NEG_INF) ? 0.f : __expf(pv[fn][r] - mnew[r]);
          pv[fn][r] = p;
          srow += p;
        }
        rsum[r] = srow;
      }
      #pragma unroll
      for (int r = 0; r < 4; ++r) {
        #pragma unroll
        for (int d = 1; d < 16; d <<= 1)
          rsum[r] += __shfl_xor(rsum[r], d);
        l[r] += rsum[r];
      }
      #pragma unroll
      for (int db = 0; db < 8; ++db)
        #pragma unroll
        for (int r = 0; r < 4; ++r)
          o[db][r] *= alpha[r];
      // P -> LDS (bf16), A-fragment layout for PV
      #pragma unroll
      for (int fn = 0; fn < 4; ++fn)
        #pragma unroll
        for (int r = 0; r < 4; ++r)
          Ps[wave][q4 * 4 + r][fn * 16 + r16] = f2b(pv[fn][r]);
    }
    __syncthreads();   // drain Ps writes (lgkmcnt(0) before barrier)
    if (active) {
      #pragma unroll
      for (int ks = 0; ks < 2; ++ks) {
        s16x8 pf = *reinterpret_cast<const s16x8*>(&Ps[wave][r16][ks * 32 + q4 * 8]);
        #pragma unroll
        for (int db = 0; db < 8; ++db) {
          s16x8 vf = *reinterpret_cast<const s16x8*>(&Vs[db * 16 + r16][ks * 32 + q4 * 8]);
          o[db] = __builtin_amdgcn_mfma_f32_16x16x32_bf16(pf, vf, o[db], 0, 0, 0);
        }
      }
    }
  }

  float rl[4];
  #pragma unroll
  for (int r = 0; r < 4; ++r) rl[r] = 1.0f / l[r];
  #pragma unroll
  for (int db = 0; db < 8; ++db)
    #pragma unroll
    for (int r = 0; r < 4; ++r) {
      int t = qt * QB + wave * 16 + q4 * 4 + r;
      int d = db * 16 + r16;
      Y[(size_t)t * (HQ_ * HD_) + h * HD_ + d] = f2b(o[db][r] * rl[r]);
    }
}

// ---------------------------------------------------------------------------
extern "C" void kernel_launch(void* const* d_in, const int* in_sizes, int n_in,
                              void* d_out, int out_size, void* d_ws, size_t ws_size,
                              hipStream_t stream) {
  const float* x  = (const float*)d_in[0];
  const float* wq = (const float*)d_in[1];
  const float* wk = (const float*)d_in[2];
  const float* wv = (const float*)d_in[3];
  const float* wo = (const float*)d_in[4];
  const float* fc = (const float*)d_in[5];
  const float* fs = (const float*)d_in[6];
  const float* kc = (const float*)d_in[7];
  const float* vc = (const float*)d_in[8];
  const int* ipos = (const int*)d_in[9];

  char* ws = (char*)d_ws;
  unsigned short* xb   = (unsigned short*)(ws);                 // 12.58 MB
  unsigned short* wqkv = (unsigned short*)(ws + 12582912);      // 37.75 MB
  unsigned short* qkv  = (unsigned short*)(ws + 50331648);      // 25.17 MB (later y)
  unsigned short* Qr   = (unsigned short*)(ws + 75497472);      // 16.78 MB
  unsigned short* Kall = (unsigned short*)(ws + 92274688);      //  8.39 MB
  unsigned short* VT   = (unsigned short*)(ws + 100663296);     //  8.39 MB (end 109.05 MB)
  unsigned short* wo_b = (unsigned short*)(ws);                 // reuse region 0 after qkv GEMM
  unsigned short* y    = qkv;                                   // reuse after rope/vt

  // converts: x, wq, wk, wv -> bf16
  k_cvt<<<6144, 256, 0, stream>>>(x, xb, 6291456 / 4);
  k_cvt<<<12288, 256, 0, stream>>>(wq, wqkv, 12582912 / 4);
  k_cvt<<<3072, 256, 0, stream>>>(wk, wqkv + 12582912, 3145728 / 4);
  k_cvt<<<3072, 256, 0, stream>>>(wv, wqkv + 15728640, 3145728 / 4);

  // fused QKV projection: qkv[2048][6144] = xb @ wqkv^T
  k_gemm_nt<true><<<16 * 48, 256, 0, stream>>>(xb, wqkv, qkv, T_, NQKV_, DIM_);

  // wo -> bf16 (region 0 is dead now)
  k_cvt<<<12288, 256, 0, stream>>>(wo, wo_b, 12582912 / 4);

  // RoPE + scatter + V transpose
  k_rope_q<<<16384, 256, 0, stream>>>(qkv, fc, fs, Qr);
  k_rope_k<<<4096, 256, 0, stream>>>(qkv, fc, fs, Kall, ipos);
  k_prefix<<<16384, 256, 0, stream>>>(kc, vc, Kall, VT, ipos);
  k_vt<<<256, 256, 0, stream>>>(qkv, VT, ipos);

  // attention -> y[2048][4096] (bf16, reuses qkv region)
  k_attn<<<dim3(HQ_, T_ / 64), 256, 0, stream>>>(Qr, Kall, VT, y, ipos);

  // output projection: out[2048][3072] = y @ wo_b^T (f32 out)
  k_gemm_nt<false><<<16 * 24, 256, 0, stream>>>(y, wo_b, d_out, T_, DIM_, HQ_ * HD_);
}

// Round 3
// 370.525 us; speedup vs baseline: 1.1440x; 1.1440x over previous
//
#include <hip/hip_runtime.h>
#include <hip/hip_bf16.h>
#include <stdint.h>

typedef float f32x4 __attribute__((ext_vector_type(4)));
typedef short s16x8 __attribute__((ext_vector_type(8)));
typedef unsigned short u16x2 __attribute__((ext_vector_type(2)));
typedef unsigned short u16x4 __attribute__((ext_vector_type(4)));

#define AS1 __attribute__((address_space(1)))
#define AS3 __attribute__((address_space(3)))

static constexpr int T_    = 2048;
static constexpr int DIM_  = 3072;
static constexpr int HQ_   = 32;
static constexpr int HKV_  = 8;
static constexpr int HD_   = 128;
static constexpr int S_    = 4096;
static constexpr int NQKV_ = HQ_ * HD_ + 2 * HKV_ * HD_;   // 6144

__device__ __forceinline__ unsigned short f2b(float f) {
  return __builtin_bit_cast(unsigned short, __float2bfloat16(f));
}
__device__ __forceinline__ float b2f(unsigned short u) {
  return __bfloat162float(__builtin_bit_cast(__hip_bfloat16, u));
}

__device__ __forceinline__ void gld_lds16(const void* g, void* l) {
  __builtin_amdgcn_global_load_lds((AS1 unsigned int*)(uintptr_t)g,
                                   (AS3 unsigned int*)l, 16, 0, 0);
}

#define FENCE() asm volatile("" ::: "memory")
#define BAR()   do { FENCE(); __builtin_amdgcn_s_barrier(); FENCE(); } while (0)
#define WAIT_LGKM0() asm volatile("s_waitcnt lgkmcnt(0)" ::: "memory")
#define WAIT_VM2()   asm volatile("s_waitcnt vmcnt(2)" ::: "memory")
#define WAIT_VM0()   asm volatile("s_waitcnt vmcnt(0)" ::: "memory")
#define SCHEDB()     __builtin_amdgcn_sched_barrier(0)

// ---------------- f32 -> bf16 convert ----------------
__global__ __launch_bounds__(256)
void k_cvt(const float* __restrict__ src, unsigned short* __restrict__ dst, int n4) {
  int i = blockIdx.x * 256 + threadIdx.x;
  if (i >= n4) return;
  float4 v = reinterpret_cast<const float4*>(src)[i];
  u16x4 o;
  o.x = f2b(v.x); o.y = f2b(v.y); o.z = f2b(v.z); o.w = f2b(v.w);
  reinterpret_cast<u16x4*>(dst)[i] = o;
}

// ---------------- 256x256 8-wave 4-phase NT GEMM (bf16 in) ------------------
// C[M][N] = A[M][K_total] * B[N][K_total]^T over K-tiles [k0, k0+KT*64).
// 512 threads = 8 waves (2M x 4N), per-wave 128x64 output.
// LDS: 2 x (A 256x64 + B 256x64) bf16 = 128 KiB, XOR-swizzled (row&7)<<4,
// staged via global_load_lds (linear dest, pre-swizzled global source).
// Counted vmcnt(2) at phases 0/3 only; raw s_barrier; setprio around MFMA.
template<bool OUT_BF16>
__global__ __launch_bounds__(512, 2)
void k_gemm256(const unsigned short* __restrict__ A,
               const unsigned short* __restrict__ B,
               void* __restrict__ Cout, int N, int K, int KT,
               int nbn, int xcdq, int k0step, int partStride) {
  __shared__ unsigned short lds_u[2][32768];           // 2 x 64 KiB
  char* ldsBase = (char*)&lds_u[0][0];

  const int bid = blockIdx.x;
  const int swz = (bid & 7) * xcdq + (bid >> 3);       // bijective: nwg % 8 == 0
  const int bm  = swz / nbn, bn = swz % nbn;
  const int tid = threadIdx.x, lane = tid & 63, wid = tid >> 6;
  const int wm  = wid >> 2, wn = wid & 3;
  const int r16 = lane & 15, q4 = lane >> 4;
  const int k0  = blockIdx.y * k0step;

  const unsigned short* Ag = A + (size_t)(bm * 256) * K + k0;
  const unsigned short* Bg = B + (size_t)(bn * 256) * K + k0;

  // staging geometry: round r covers 64 rows (8 KiB); thread -> (row, col16)
  const int srow   = tid >> 3;                          // 0..63
  const int scol16 = (tid & 7) ^ (srow & 7);            // pre-swizzled source col
  const int scol   = scol16 * 8;                        // elements

  f32x4 acc[8][4] = {};

  auto stageA = [&](int c, int r, int t) {
    gld_lds16(Ag + (size_t)(r * 64 + srow) * K + t * 64 + scol,
              ldsBase + c * 65536 + r * 8192 + tid * 16);
  };
  auto stageB = [&](int c, int r, int t) {
    gld_lds16(Bg + (size_t)(r * 64 + srow) * K + t * 64 + scol,
              ldsBase + c * 65536 + 32768 + r * 8192 + tid * 16);
  };
  auto stagePair = [&](int c, int pair, int t) {
    switch (pair) {
      case 0: stageB(c, 0, t); stageB(c, 1, t); break;
      case 1: stageB(c, 2, t); stageB(c, 3, t); break;
      case 2: stageA(c, 0, t); stageA(c, 2, t); break;
      case 3: stageA(c, 1, t); stageA(c, 3, t); break;
    }
  };

  // prologue: stage tile 0 into buf 0; leave last pair (A rounds 1,3) in flight
  stagePair(0, 0, 0); stagePair(0, 1, 0); stagePair(0, 2, 0); stagePair(0, 3, 0);
  WAIT_VM2();
  BAR();

  for (int t = 0; t < KT; ++t) {
    const int  c = t & 1;
    const bool hasNext = (t + 1 < KT);
    char* base = ldsBase + c * 65536;
    #pragma unroll
    for (int p = 0; p < 4; ++p) {
      const int rh = p & 1, ch = p >> 1;
      s16x8 af[4][2], bf[2][2];
      #pragma unroll
      for (int i = 0; i < 4; ++i) {
        const int arow = wm * 128 + rh * 64 + i * 16 + r16;
        #pragma unroll
        for (int kk = 0; kk < 2; ++kk)
          af[i][kk] = *(const s16x8*)(base + arow * 128 +
                                      (((kk * 4 + q4) ^ (arow & 7)) << 4));
      }
      #pragma unroll
      for (int j = 0; j < 2; ++j) {
        const int brow = wn * 64 + ch * 32 + j * 16 + r16;
        #pragma unroll
        for (int kk = 0; kk < 2; ++kk)
          bf[j][kk] = *(const s16x8*)(base + 32768 + brow * 128 +
                                      (((kk * 4 + q4) ^ (brow & 7)) << 4));
      }
      if (hasNext) stagePair(c ^ 1, p, t + 1);
      BAR();
      WAIT_LGKM0();
      SCHEDB();
      __builtin_amdgcn_s_setprio(1);
      #pragma unroll
      for (int i = 0; i < 4; ++i)
        #pragma unroll
        for (int j = 0; j < 2; ++j)
          #pragma unroll
          for (int kk = 0; kk < 2; ++kk)
            acc[rh * 4 + i][ch * 2 + j] = __builtin_amdgcn_mfma_f32_16x16x32_bf16(
                af[i][kk], bf[j][kk], acc[rh * 4 + i][ch * 2 + j], 0, 0, 0);
      __builtin_amdgcn_s_setprio(0);
      if (p == 0) { if (hasNext) WAIT_VM2(); else WAIT_VM0(); }
      if (p == 3 && hasNext) WAIT_VM2();
      BAR();
    }
  }

  // epilogue
  #pragma unroll
  for (int fi = 0; fi < 8; ++fi) {
    const int row = bm * 256 + wm * 128 + (fi >> 2) * 64 + (fi & 3) * 16 + q4 * 4;
    #pragma unroll
    for (int fj = 0; fj < 4; ++fj) {
      const int col = bn * 256 + wn * 64 + (fj >> 1) * 32 + (fj & 1) * 16 + r16;
      if constexpr (OUT_BF16) {
        unsigned short* C = (unsigned short*)Cout;
        #pragma unroll
        for (int rr = 0; rr < 4; ++rr)
          C[(size_t)(row + rr) * N + col] = f2b(acc[fi][fj][rr]);
      } else {
        float* C = (float*)Cout + (size_t)blockIdx.y * partStride;
        #pragma unroll
        for (int rr = 0; rr < 4; ++rr)
          C[(size_t)(row + rr) * N + col] = acc[fi][fj][rr];
      }
    }
  }
}

// ---------------- split-K reduce: out = p0 + p1 (f32) ----------------------
__global__ __launch_bounds__(256)
void k_add(const f32x4* __restrict__ a, const f32x4* __restrict__ b,
           f32x4* __restrict__ o, int n4) {
  int i = blockIdx.x * 256 + threadIdx.x;
  const int stride = gridDim.x * 256;
  for (; i < n4; i += stride) o[i] = a[i] + b[i];
}

// ---------------- RoPE on Q: qkv[t][h*128+d] -> Qr[h][t][d] ----------------
__global__ __launch_bounds__(256)
void k_rope_q(const unsigned short* __restrict__ qkv,
              const float* __restrict__ fc, const float* __restrict__ fs,
              unsigned short* __restrict__ Qr) {
  int idx = blockIdx.x * 256 + threadIdx.x;   // T*HQ*64
  int t   = idx >> 11;
  int rem = idx & 2047;
  int h   = rem >> 6;
  int d0  = (rem & 63) << 1;
  size_t qoff = (size_t)t * NQKV_ + h * HD_ + d0;
  u16x2 xv = *reinterpret_cast<const u16x2*>(&qkv[qoff]);
  float x0 = b2f(xv.x), x1 = b2f(xv.y);
  float c0 = fc[t * HD_ + d0], c1 = fc[t * HD_ + d0 + 1];
  float s0 = fs[t * HD_ + d0], s1 = fs[t * HD_ + d0 + 1];
  u16x2 o;
  o.x = f2b(x0 * c0 - x1 * s0);
  o.y = f2b(x1 * c1 + x0 * s1);
  *reinterpret_cast<u16x2*>(&Qr[((size_t)h * T_ + t) * HD_ + d0]) = o;
}

// ---------------- RoPE on K + scatter into Kall[hk][sp+t][d] ---------------
__global__ __launch_bounds__(256)
void k_rope_k(const unsigned short* __restrict__ qkv,
              const float* __restrict__ fc, const float* __restrict__ fs,
              unsigned short* __restrict__ Kall, const int* __restrict__ ipos) {
  int idx = blockIdx.x * 256 + threadIdx.x;   // T*HKV*64
  int t   = idx >> 9;
  int rem = idx & 511;
  int hk  = rem >> 6;
  int d0  = (rem & 63) << 1;
  int sp  = ipos[0];
  size_t qoff = (size_t)t * NQKV_ + HQ_ * HD_ + hk * HD_ + d0;
  u16x2 xv = *reinterpret_cast<const u16x2*>(&qkv[qoff]);
  float x0 = b2f(xv.x), x1 = b2f(xv.y);
  float c0 = fc[t * HD_ + d0], c1 = fc[t * HD_ + d0 + 1];
  float s0 = fs[t * HD_ + d0], s1 = fs[t * HD_ + d0 + 1];
  unsigned short o0 = f2b(x0 * c0 - x1 * s0);
  unsigned short o1 = f2b(x1 * c1 + x0 * s1);
  size_t ooff = ((size_t)hk * S_ + sp + t) * HD_ + d0;
  Kall[ooff] = o0; Kall[ooff + 1] = o1;
}

// ---------------- cache prefix (s < sp) into Kall / VT ---------------------
__global__ __launch_bounds__(256)
void k_prefix(const float* __restrict__ kc, const float* __restrict__ vc,
              unsigned short* __restrict__ Kall, unsigned short* __restrict__ VT,
              const int* __restrict__ ipos) {
  int idx = blockIdx.x * 256 + threadIdx.x;   // S*HKV*HD
  int s   = idx >> 10;
  int sp  = ipos[0];
  if (s >= sp) return;
  int rem = idx & 1023;
  int hk  = rem >> 7;
  int d   = rem & 127;
  Kall[((size_t)hk * S_ + s) * HD_ + d] = f2b(kc[((size_t)s * HKV_ + hk) * HD_ + d]);
  VT[((size_t)hk * HD_ + d) * S_ + s]   = f2b(vc[((size_t)s * HKV_ + hk) * HD_ + d]);
}

// ---------------- V transpose: qkv v-section -> VT[hk][d][sp+t] ------------
__global__ __launch_bounds__(256)
void k_vt(const unsigned short* __restrict__ qkv,
          unsigned short* __restrict__ VT, const int* __restrict__ ipos) {
  int hk = blockIdx.x >> 5;     // 0..7
  int tt = blockIdx.x & 31;     // 0..31 (tiles of 64 t)
  int sp = ipos[0];
  __shared__ unsigned short lds[64][136];
  int tid = threadIdx.x;
  #pragma unroll
  for (int p = 0; p < 4; ++p) {
    int e   = p * 256 + tid;            // 0..1023
    int tr  = e >> 4;                   // 0..63
    int col = (e & 15) << 3;            // 0..120
    *reinterpret_cast<s16x8*>(&lds[tr][col]) =
        *reinterpret_cast<const s16x8*>(&qkv[(size_t)(tt * 64 + tr) * NQKV_ + (HQ_ + HKV_) * HD_ + hk * HD_ + col]);
  }
  __syncthreads();
  #pragma unroll
  for (int p = 0; p < 32; ++p) {
    int e = p * 256 + tid;              // 0..8191
    int d = e >> 6;                     // 0..127
    int t = e & 63;
    VT[((size_t)hk * HD_ + d) * S_ + sp + tt * 64 + t] = lds[t][d];
  }
}

// ---------------- flash attention (GQA, causal) ----------------------------
__global__ __launch_bounds__(256)
void k_attn(const unsigned short* __restrict__ Qr,
            const unsigned short* __restrict__ Kall,
            const unsigned short* __restrict__ VT,
            unsigned short* __restrict__ Y,
            const int* __restrict__ ipos) {
  constexpr int QB = 64, KB = 64;
  const int h    = blockIdx.x;
  const int qt   = blockIdx.y;
  const int hk   = h >> 2;
  const int sp   = ipos[0];
  const int tid  = threadIdx.x, lane = tid & 63, wave = tid >> 6;
  const int r16  = lane & 15, q4 = lane >> 4;
  const float NEG_INF = -__builtin_inff();

  __shared__ unsigned short Ks[KB][HD_ + 8];      // 64 x 136
  __shared__ unsigned short Vs[HD_][KB + 8];      // 128 x 72
  __shared__ unsigned short Ps[4][16][KB + 8];    // per-wave 16 x 72

  const int qrow = qt * QB + wave * 16 + r16;
  s16x8 qf[4];
  const unsigned short* qp = Qr + ((size_t)h * T_ + qrow) * HD_;
  #pragma unroll
  for (int ki = 0; ki < 4; ++ki)
    qf[ki] = *reinterpret_cast<const s16x8*>(qp + ki * 32 + q4 * 8);

  f32x4 o[8] = {};
  float m[4], l[4];
  #pragma unroll
  for (int r = 0; r < 4; ++r) { m[r] = NEG_INF; l[r] = 0.f; }

  const int qpos_wave_max = sp + qt * QB + wave * 16 + 15;
  int jmax = (sp + qt * QB + QB - 1) >> 6;
  if (jmax > S_ / KB - 1) jmax = S_ / KB - 1;
  const float scale = 0.08838834764831845f;

  const unsigned short* Kbase = Kall + (size_t)hk * S_ * HD_;
  const unsigned short* Vbase = VT + (size_t)hk * HD_ * S_;

  for (int j = 0; j <= jmax; ++j) {
    s16x8 kreg[4], vreg[4];
    #pragma unroll
    for (int p = 0; p < 4; ++p) {
      int e  = p * 256 + tid;
      int kr = e >> 4, kc = (e & 15) << 3;
      kreg[p] = *reinterpret_cast<const s16x8*>(Kbase + (size_t)(j * KB + kr) * HD_ + kc);
      int vd = e >> 3, vs = (e & 7) << 3;
      vreg[p] = *reinterpret_cast<const s16x8*>(Vbase + (size_t)vd * S_ + j * KB + vs);
    }
    __syncthreads();
    #pragma unroll
    for (int p = 0; p < 4; ++p) {
      int e  = p * 256 + tid;
      int kr = e >> 4, kc = (e & 15) << 3;
      *reinterpret_cast<s16x8*>(&Ks[kr][kc]) = kreg[p];
      int vd = e >> 3, vs = (e & 7) << 3;
      *reinterpret_cast<s16x8*>(&Vs[vd][vs]) = vreg[p];
    }
    __syncthreads();

    const bool active = (j * KB <= qpos_wave_max);
    if (active) {
      f32x4 sfr[4];
      #pragma unroll
      for (int fn = 0; fn < 4; ++fn) {
        sfr[fn] = f32x4{0.f, 0.f, 0.f, 0.f};
        #pragma unroll
        for (int ki = 0; ki < 4; ++ki) {
          s16x8 kf = *reinterpret_cast<const s16x8*>(&Ks[fn * 16 + r16][ki * 32 + q4 * 8]);
          sfr[fn] = __builtin_amdgcn_mfma_f32_16x16x32_bf16(qf[ki], kf, sfr[fn], 0, 0, 0);
        }
      }
      float pv[4][4];
      float mnew[4];
      #pragma unroll
      for (int r = 0; r < 4; ++r) mnew[r] = m[r];
      #pragma unroll
      for (int fn = 0; fn < 4; ++fn) {
        int kpos = j * KB + fn * 16 + r16;
        #pragma unroll
        for (int r = 0; r < 4; ++r) {
          int qpos = sp + qt * QB + wave * 16 + q4 * 4 + r;
          float s = sfr[fn][r] * scale;
          s = (kpos <= qpos) ? s : NEG_INF;
          pv[fn][r] = s;
          mnew[r] = fmaxf(mnew[r], s);
        }
      }
      #pragma unroll
      for (int r = 0; r < 4; ++r)
        #pragma unroll
        for (int d = 1; d < 16; d <<= 1)
          mnew[r] = fmaxf(mnew[r], __shfl_xor(mnew[r], d));
      float alpha[4], rsum[4];
      #pragma unroll
      for (int r = 0; r < 4; ++r) {
        alpha[r] = (mnew[r] == NEG_INF) ? 1.0f : __expf(m[r] - mnew[r]);
        m[r] = mnew[r];
        l[r] *= alpha[r];
        float srow = 0.f;
        #pragma unroll
        for (int fn = 0; fn < 4; ++fn) {
          float p = (pv[fn][r] == NEG_INF) ? 0.f : __expf(pv[fn][r] - mnew[r]);
          pv[fn][r] = p;
          srow += p;
        }
        rsum[r] = srow;
      }
      #pragma unroll
      for (int r = 0; r < 4; ++r) {
        #pragma unroll
        for (int d = 1; d < 16; d <<= 1)
          rsum[r] += __shfl_xor(rsum[r], d);
        l[r] += rsum[r];
      }
      #pragma unroll
      for (int db = 0; db < 8; ++db)
        #pragma unroll
        for (int r = 0; r < 4; ++r)
          o[db][r] *= alpha[r];
      #pragma unroll
      for (int fn = 0; fn < 4; ++fn)
        #pragma unroll
        for (int r = 0; r < 4; ++r)
          Ps[wave][q4 * 4 + r][fn * 16 + r16] = f2b(pv[fn][r]);
    }
    __syncthreads();
    if (active) {
      #pragma unroll
      for (int ks = 0; ks < 2; ++ks) {
        s16x8 pf = *reinterpret_cast<const s16x8*>(&Ps[wave][r16][ks * 32 + q4 * 8]);
        #pragma unroll
        for (int db = 0; db < 8; ++db) {
          s16x8 vf = *reinterpret_cast<const s16x8*>(&Vs[db * 16 + r16][ks * 32 + q4 * 8]);
          o[db] = __builtin_amdgcn_mfma_f32_16x16x32_bf16(pf, vf, o[db], 0, 0, 0);
        }
      }
    }
  }

  float rl[4];
  #pragma unroll
  for (int r = 0; r < 4; ++r) rl[r] = 1.0f / l[r];
  #pragma unroll
  for (int db = 0; db < 8; ++db)
    #pragma unroll
    for (int r = 0; r < 4; ++r) {
      int t = qt * QB + wave * 16 + q4 * 4 + r;
      int d = db * 16 + r16;
      Y[(size_t)t * (HQ_ * HD_) + h * HD_ + d] = f2b(o[db][r] * rl[r]);
    }
}

// ---------------------------------------------------------------------------
extern "C" void kernel_launch(void* const* d_in, const int* in_sizes, int n_in,
                              void* d_out, int out_size, void* d_ws, size_t ws_size,
                              hipStream_t stream) {
  const float* x  = (const float*)d_in[0];
  const float* wq = (const float*)d_in[1];
  const float* wk = (const float*)d_in[2];
  const float* wv = (const float*)d_in[3];
  const float* wo = (const float*)d_in[4];
  const float* fc = (const float*)d_in[5];
  const float* fs = (const float*)d_in[6];
  const float* kc = (const float*)d_in[7];
  const float* vc = (const float*)d_in[8];
  const int* ipos = (const int*)d_in[9];

  char* ws = (char*)d_ws;
  unsigned short* xb   = (unsigned short*)(ws);                 // [0, 12.58 MB)
  unsigned short* wqkv = (unsigned short*)(ws + 12582912);      // [12.58, 50.33)
  unsigned short* qkv  = (unsigned short*)(ws + 50331648);      // [50.33, 75.50) (later y)
  unsigned short* Qr   = (unsigned short*)(ws + 75497472);      // [75.50, 92.27)
  unsigned short* Kall = (unsigned short*)(ws + 92274688);      // [92.27, 100.66)
  unsigned short* VT   = (unsigned short*)(ws + 100663296);     // [100.66, 109.05)
  unsigned short* wo_b = (unsigned short*)(ws);                 // reuse region 0 after QKV GEMM
  unsigned short* y    = qkv;                                   // reuse after rope/vt

  // split-K partials: z=0 in dead wqkv region [12.58, 37.75 MB);
  // z=1 at part0 + partStride elems = ws+75497472 -> dead Qr+Kall [75.50, 100.66 MB).
  // (round-2 bug: z=1 landed on y and k_add read a third, stale region)
  float* part0 = (float*)(ws + 12582912);
  float* part1 = (float*)(ws + 75497472);
  const int partStrideElems = (75497472 - 12582912) / 4;        // 15728640

  // converts: x, wq, wk, wv -> bf16
  k_cvt<<<6144, 256, 0, stream>>>(x, xb, 6291456 / 4);
  k_cvt<<<12288, 256, 0, stream>>>(wq, wqkv, 12582912 / 4);
  k_cvt<<<3072, 256, 0, stream>>>(wk, wqkv + 12582912, 3145728 / 4);
  k_cvt<<<3072, 256, 0, stream>>>(wv, wqkv + 15728640, 3145728 / 4);

  // fused QKV projection: qkv[2048][6144] = xb @ wqkv^T   (grid 8x24=192)
  k_gemm256<true><<<192, 512, 0, stream>>>(xb, wqkv, qkv, NQKV_, DIM_, 48, 24, 24, 0, 0);

  // wo -> bf16 (region 0 dead now)
  k_cvt<<<12288, 256, 0, stream>>>(wo, wo_b, 12582912 / 4);

  // RoPE + scatter + V transpose
  k_rope_q<<<16384, 256, 0, stream>>>(qkv, fc, fs, Qr);
  k_rope_k<<<4096, 256, 0, stream>>>(qkv, fc, fs, Kall, ipos);
  k_prefix<<<16384, 256, 0, stream>>>(kc, vc, Kall, VT, ipos);
  k_vt<<<256, 256, 0, stream>>>(qkv, VT, ipos);

  // attention -> y[2048][4096] (bf16)
  k_attn<<<dim3(HQ_, T_ / 64), 256, 0, stream>>>(Qr, Kall, VT, y, ipos);

  // output projection, split-K=2: part[z] = y @ wo_b^T (K half each)
  k_gemm256<false><<<dim3(96, 2), 512, 0, stream>>>(y, wo_b, part0, DIM_, HQ_ * HD_,
                                                    32, 12, 12, 2048, partStrideElems);
  // reduce: out = part0 + part1
  k_add<<<1024, 256, 0, stream>>>((const f32x4*)part0, (const f32x4*)part1,
                                  (f32x4*)d_out, 6291456 / 4);
}

// Round 4
// 334.932 us; speedup vs baseline: 1.2656x; 1.1063x over previous
//
#include <hip/hip_runtime.h>
#include <hip/hip_bf16.h>
#include <stdint.h>

typedef float f32x4 __attribute__((ext_vector_type(4)));
typedef short s16x8 __attribute__((ext_vector_type(8)));
typedef short s16x4 __attribute__((ext_vector_type(4)));
typedef unsigned short u16x2 __attribute__((ext_vector_type(2)));
typedef unsigned short u16x4 __attribute__((ext_vector_type(4)));

#define AS1 __attribute__((address_space(1)))
#define AS3 __attribute__((address_space(3)))

static constexpr int T_    = 2048;
static constexpr int DIM_  = 3072;
static constexpr int HQ_   = 32;
static constexpr int HKV_  = 8;
static constexpr int HD_   = 128;
static constexpr int S_    = 4096;
static constexpr int NQKV_ = HQ_ * HD_ + 2 * HKV_ * HD_;   // 6144

__device__ __forceinline__ unsigned short f2b(float f) {
  return __builtin_bit_cast(unsigned short, __float2bfloat16(f));
}
__device__ __forceinline__ float b2f(unsigned short u) {
  return __bfloat162float(__builtin_bit_cast(__hip_bfloat16, u));
}
__device__ __forceinline__ float exp2a(float x) {      // exact v_exp_f32: 2^x
  float r; asm("v_exp_f32 %0, %1" : "=v"(r) : "v"(x)); return r;
}

__device__ __forceinline__ void gld_lds16(const void* g, void* l) {
  __builtin_amdgcn_global_load_lds((AS1 unsigned int*)(uintptr_t)g,
                                   (AS3 unsigned int*)l, 16, 0, 0);
}

#define FENCE() asm volatile("" ::: "memory")
#define BAR()   do { FENCE(); __builtin_amdgcn_s_barrier(); FENCE(); } while (0)
#define WAIT_LGKM0() asm volatile("s_waitcnt lgkmcnt(0)" ::: "memory")
#define WAIT_VM2()   asm volatile("s_waitcnt vmcnt(2)" ::: "memory")
#define WAIT_VM0()   asm volatile("s_waitcnt vmcnt(0)" ::: "memory")
#define SCHEDB()     __builtin_amdgcn_sched_barrier(0)

// ---------------- f32 -> bf16 convert ----------------
__global__ __launch_bounds__(256)
void k_cvt(const float* __restrict__ src, unsigned short* __restrict__ dst, int n4) {
  int i = blockIdx.x * 256 + threadIdx.x;
  if (i >= n4) return;
  float4 v = reinterpret_cast<const float4*>(src)[i];
  u16x4 o;
  o.x = f2b(v.x); o.y = f2b(v.y); o.z = f2b(v.z); o.w = f2b(v.w);
  reinterpret_cast<u16x4*>(dst)[i] = o;
}

// ---------------- 256x256 8-wave 4-phase NT GEMM (bf16 in) ------------------
template<bool OUT_BF16>
__global__ __launch_bounds__(512, 2)
void k_gemm256(const unsigned short* __restrict__ A,
               const unsigned short* __restrict__ B,
               void* __restrict__ Cout, int N, int K, int KT,
               int nbn, int xcdq, int k0step, int partStride) {
  __shared__ unsigned short lds_u[2][32768];           // 2 x 64 KiB
  char* ldsBase = (char*)&lds_u[0][0];

  const int bid = blockIdx.x;
  const int swz = (bid & 7) * xcdq + (bid >> 3);       // bijective: nwg % 8 == 0
  const int bm  = swz / nbn, bn = swz % nbn;
  const int tid = threadIdx.x, lane = tid & 63, wid = tid >> 6;
  const int wm  = wid >> 2, wn = wid & 3;
  const int r16 = lane & 15, q4 = lane >> 4;
  const int k0  = blockIdx.y * k0step;

  const unsigned short* Ag = A + (size_t)(bm * 256) * K + k0;
  const unsigned short* Bg = B + (size_t)(bn * 256) * K + k0;

  const int srow   = tid >> 3;                          // 0..63
  const int scol16 = (tid & 7) ^ (srow & 7);            // pre-swizzled source col
  const int scol   = scol16 * 8;                        // elements

  f32x4 acc[8][4] = {};

  auto stageA = [&](int c, int r, int t) {
    gld_lds16(Ag + (size_t)(r * 64 + srow) * K + t * 64 + scol,
              ldsBase + c * 65536 + r * 8192 + tid * 16);
  };
  auto stageB = [&](int c, int r, int t) {
    gld_lds16(Bg + (size_t)(r * 64 + srow) * K + t * 64 + scol,
              ldsBase + c * 65536 + 32768 + r * 8192 + tid * 16);
  };
  auto stagePair = [&](int c, int pair, int t) {
    switch (pair) {
      case 0: stageB(c, 0, t); stageB(c, 1, t); break;
      case 1: stageB(c, 2, t); stageB(c, 3, t); break;
      case 2: stageA(c, 0, t); stageA(c, 2, t); break;
      case 3: stageA(c, 1, t); stageA(c, 3, t); break;
    }
  };

  stagePair(0, 0, 0); stagePair(0, 1, 0); stagePair(0, 2, 0); stagePair(0, 3, 0);
  WAIT_VM2();
  BAR();

  for (int t = 0; t < KT; ++t) {
    const int  c = t & 1;
    const bool hasNext = (t + 1 < KT);
    char* base = ldsBase + c * 65536;
    #pragma unroll
    for (int p = 0; p < 4; ++p) {
      const int rh = p & 1, ch = p >> 1;
      s16x8 af[4][2], bf[2][2];
      #pragma unroll
      for (int i = 0; i < 4; ++i) {
        const int arow = wm * 128 + rh * 64 + i * 16 + r16;
        #pragma unroll
        for (int kk = 0; kk < 2; ++kk)
          af[i][kk] = *(const s16x8*)(base + arow * 128 +
                                      (((kk * 4 + q4) ^ (arow & 7)) << 4));
      }
      #pragma unroll
      for (int j = 0; j < 2; ++j) {
        const int brow = wn * 64 + ch * 32 + j * 16 + r16;
        #pragma unroll
        for (int kk = 0; kk < 2; ++kk)
          bf[j][kk] = *(const s16x8*)(base + 32768 + brow * 128 +
                                      (((kk * 4 + q4) ^ (brow & 7)) << 4));
      }
      if (hasNext) stagePair(c ^ 1, p, t + 1);
      BAR();
      WAIT_LGKM0();
      SCHEDB();
      __builtin_amdgcn_s_setprio(1);
      #pragma unroll
      for (int i = 0; i < 4; ++i)
        #pragma unroll
        for (int j = 0; j < 2; ++j)
          #pragma unroll
          for (int kk = 0; kk < 2; ++kk)
            acc[rh * 4 + i][ch * 2 + j] = __builtin_amdgcn_mfma_f32_16x16x32_bf16(
                af[i][kk], bf[j][kk], acc[rh * 4 + i][ch * 2 + j], 0, 0, 0);
      __builtin_amdgcn_s_setprio(0);
      if (p == 0) { if (hasNext) WAIT_VM2(); else WAIT_VM0(); }
      if (p == 3 && hasNext) WAIT_VM2();
      BAR();
    }
  }

  #pragma unroll
  for (int fi = 0; fi < 8; ++fi) {
    const int row = bm * 256 + wm * 128 + (fi >> 2) * 64 + (fi & 3) * 16 + q4 * 4;
    #pragma unroll
    for (int fj = 0; fj < 4; ++fj) {
      const int col = bn * 256 + wn * 64 + (fj >> 1) * 32 + (fj & 1) * 16 + r16;
      if constexpr (OUT_BF16) {
        unsigned short* C = (unsigned short*)Cout;
        #pragma unroll
        for (int rr = 0; rr < 4; ++rr)
          C[(size_t)(row + rr) * N + col] = f2b(acc[fi][fj][rr]);
      } else {
        float* C = (float*)Cout + (size_t)blockIdx.y * partStride;
        #pragma unroll
        for (int rr = 0; rr < 4; ++rr)
          C[(size_t)(row + rr) * N + col] = acc[fi][fj][rr];
      }
    }
  }
}

// ---------------- split-K reduce: out = p0 + p1 (f32) ----------------------
__global__ __launch_bounds__(256)
void k_add(const f32x4* __restrict__ a, const f32x4* __restrict__ b,
           f32x4* __restrict__ o, int n4) {
  int i = blockIdx.x * 256 + threadIdx.x;
  const int stride = gridDim.x * 256;
  for (; i < n4; i += stride) o[i] = a[i] + b[i];
}

// ---------------- RoPE on Q: qkv[t][h*128+d] -> Qr[h][t][d] ----------------
__global__ __launch_bounds__(256)
void k_rope_q(const unsigned short* __restrict__ qkv,
              const float* __restrict__ fc, const float* __restrict__ fs,
              unsigned short* __restrict__ Qr) {
  int idx = blockIdx.x * 256 + threadIdx.x;   // T*HQ*64
  int t   = idx >> 11;
  int rem = idx & 2047;
  int h   = rem >> 6;
  int d0  = (rem & 63) << 1;
  size_t qoff = (size_t)t * NQKV_ + h * HD_ + d0;
  u16x2 xv = *reinterpret_cast<const u16x2*>(&qkv[qoff]);
  float x0 = b2f(xv.x), x1 = b2f(xv.y);
  float c0 = fc[t * HD_ + d0], c1 = fc[t * HD_ + d0 + 1];
  float s0 = fs[t * HD_ + d0], s1 = fs[t * HD_ + d0 + 1];
  u16x2 o;
  o.x = f2b(x0 * c0 - x1 * s0);
  o.y = f2b(x1 * c1 + x0 * s1);
  *reinterpret_cast<u16x2*>(&Qr[((size_t)h * T_ + t) * HD_ + d0]) = o;
}

// ---------------- RoPE on K + scatter into Kall[hk][sp+t][d] ---------------
__global__ __launch_bounds__(256)
void k_rope_k(const unsigned short* __restrict__ qkv,
              const float* __restrict__ fc, const float* __restrict__ fs,
              unsigned short* __restrict__ Kall, const int* __restrict__ ipos) {
  int idx = blockIdx.x * 256 + threadIdx.x;   // T*HKV*64
  int t   = idx >> 9;
  int rem = idx & 511;
  int hk  = rem >> 6;
  int d0  = (rem & 63) << 1;
  int sp  = ipos[0];
  size_t qoff = (size_t)t * NQKV_ + HQ_ * HD_ + hk * HD_ + d0;
  u16x2 xv = *reinterpret_cast<const u16x2*>(&qkv[qoff]);
  float x0 = b2f(xv.x), x1 = b2f(xv.y);
  float c0 = fc[t * HD_ + d0], c1 = fc[t * HD_ + d0 + 1];
  float s0 = fs[t * HD_ + d0], s1 = fs[t * HD_ + d0 + 1];
  unsigned short o0 = f2b(x0 * c0 - x1 * s0);
  unsigned short o1 = f2b(x1 * c1 + x0 * s1);
  size_t ooff = ((size_t)hk * S_ + sp + t) * HD_ + d0;
  Kall[ooff] = o0; Kall[ooff + 1] = o1;
}

// ---------------- cache prefix (s < sp) into Kall / VT (grid-stride) -------
__global__ __launch_bounds__(256)
void k_prefix(const float* __restrict__ kc, const float* __restrict__ vc,
              unsigned short* __restrict__ Kall, unsigned short* __restrict__ VT,
              const int* __restrict__ ipos) {
  int sp = ipos[0];
  int total = sp * HKV_ * HD_;
  for (int idx = blockIdx.x * 256 + threadIdx.x; idx < total;
       idx += gridDim.x * 256) {
    int s   = idx >> 10;
    int rem = idx & 1023;
    int hk  = rem >> 7;
    int d   = rem & 127;
    Kall[((size_t)hk * S_ + s) * HD_ + d] = f2b(kc[((size_t)s * HKV_ + hk) * HD_ + d]);
    VT[((size_t)hk * HD_ + d) * S_ + s]   = f2b(vc[((size_t)s * HKV_ + hk) * HD_ + d]);
  }
}

// ---------------- V transpose: qkv v-section -> VT[hk][d][sp+t] ------------
__global__ __launch_bounds__(256)
void k_vt(const unsigned short* __restrict__ qkv,
          unsigned short* __restrict__ VT, const int* __restrict__ ipos) {
  int hk = blockIdx.x >> 5;     // 0..7
  int tt = blockIdx.x & 31;     // 0..31 (tiles of 64 t)
  int sp = ipos[0];
  __shared__ unsigned short lds[64][136];
  int tid = threadIdx.x;
  #pragma unroll
  for (int p = 0; p < 4; ++p) {
    int e   = p * 256 + tid;            // 0..1023
    int tr  = e >> 4;                   // 0..63
    int col = (e & 15) << 3;            // 0..120
    *reinterpret_cast<s16x8*>(&lds[tr][col]) =
        *reinterpret_cast<const s16x8*>(&qkv[(size_t)(tt * 64 + tr) * NQKV_ + (HQ_ + HKV_) * HD_ + hk * HD_ + col]);
  }
  __syncthreads();
  #pragma unroll
  for (int p = 0; p < 32; ++p) {
    int e = p * 256 + tid;              // 0..8191
    int d = e >> 6;                     // 0..127
    int t = e & 63;
    VT[((size_t)hk * HD_ + d) * S_ + sp + tt * 64 + t] = lds[t][d];
  }
}

// ---------------- flash attention v2: swapped QK^T, in-register softmax ----
// grid: 1024 1-D blocks; bid -> (hk, head, qt) so each XCD's L2 keeps one
// kv-head's K+V (2 MB). 4 waves x 16 q-rows, KVBLK=64.
// QK^T = mfma(K,Q): lane holds q = lane&15, kpos = j*64+fn*16+4*q4+reg.
// Softmax per-lane scalars (m,l), log2 domain, defer-max THR=8.
// P packs in-register into 16x16x32 A-frags; V-frags via 2x ds_read_b64 with
// matching k-interleave -> no P LDS roundtrip, 2 barriers/tile.
__global__ __launch_bounds__(256, 4)
void k_attn(const unsigned short* __restrict__ Qr,
            const unsigned short* __restrict__ Kall,
            const unsigned short* __restrict__ VT,
            unsigned short* __restrict__ Y,
            const int* __restrict__ ipos) {
  constexpr int QB = 64, KB = 64;
  const int bid  = blockIdx.x;
  const int hk   = bid & 7;
  const int j2   = bid >> 3;
  const int h    = hk * 4 + (j2 & 3);
  const int qt   = j2 >> 2;
  const int sp   = ipos[0];
  const int tid  = threadIdx.x, lane = tid & 63, wave = tid >> 6;
  const int r16  = lane & 15, q4 = lane >> 4;
  const float NEG_INF = -__builtin_inff();
  const float MINIT   = -1.0e30f;          // finite init: avoids NaN in exp2 paths

  __shared__ unsigned short Ks[KB][HD_ + 8];      // 64 x 136
  __shared__ unsigned short Vs[HD_][KB + 8];      // 128 x 72

  const int qbase = qt * QB + wave * 16;
  s16x8 qf[4];
  const unsigned short* qp = Qr + ((size_t)h * T_ + qbase + r16) * HD_;
  #pragma unroll
  for (int ki = 0; ki < 4; ++ki)
    qf[ki] = *reinterpret_cast<const s16x8*>(qp + ki * 32 + q4 * 8);

  f32x4 o[8] = {};
  float m = MINIT, l = 0.f;
  const int qpos = sp + qbase + r16;              // this lane's softmax q-row
  const int qpos_wave_max = sp + qbase + 15;
  int jmax = (sp + qt * QB + QB - 1) >> 6;
  if (jmax > S_ / KB - 1) jmax = S_ / KB - 1;
  const float scale2 = 0.12751744416312068f;      // 1/sqrt(128) * log2(e)

  const unsigned short* Kbase = Kall + (size_t)hk * S_ * HD_;
  const unsigned short* Vbase = VT + (size_t)hk * HD_ * S_;

  for (int j = 0; j <= jmax; ++j) {
    s16x8 kreg[4], vreg[4];
    #pragma unroll
    for (int p = 0; p < 4; ++p) {
      int e  = p * 256 + tid;
      int kr = e >> 4, kc = (e & 15) << 3;
      kreg[p] = *reinterpret_cast<const s16x8*>(Kbase + (size_t)(j * KB + kr) * HD_ + kc);
      int vd = e >> 3, vs = (e & 7) << 3;
      vreg[p] = *reinterpret_cast<const s16x8*>(Vbase + (size_t)vd * S_ + j * KB + vs);
    }
    __syncthreads();
    #pragma unroll
    for (int p = 0; p < 4; ++p) {
      int e  = p * 256 + tid;
      int kr = e >> 4, kc = (e & 15) << 3;
      *reinterpret_cast<s16x8*>(&Ks[kr][kc]) = kreg[p];
      int vd = e >> 3, vs = (e & 7) << 3;
      *reinterpret_cast<s16x8*>(&Vs[vd][vs]) = vreg[p];
    }
    __syncthreads();

    const bool active = (j * KB <= qpos_wave_max);
    if (active) {
      // S^T = K Q^T : lane -> q=r16, kpos = j*64 + fn*16 + 4*q4 + reg
      f32x4 sfr[4];
      #pragma unroll
      for (int fn = 0; fn < 4; ++fn) {
        sfr[fn] = f32x4{0.f, 0.f, 0.f, 0.f};
        #pragma unroll
        for (int ki = 0; ki < 4; ++ki) {
          s16x8 kf = *reinterpret_cast<const s16x8*>(&Ks[fn * 16 + r16][ki * 32 + q4 * 8]);
          sfr[fn] = __builtin_amdgcn_mfma_f32_16x16x32_bf16(kf, qf[ki], sfr[fn], 0, 0, 0);
        }
      }
      float p[16];
      const bool needMask = (j * KB + KB - 1) > (sp + qbase);   // wave-uniform
      if (needMask) {
        const int kb = j * KB + q4 * 4;
        #pragma unroll
        for (int fn = 0; fn < 4; ++fn)
          #pragma unroll
          for (int r = 0; r < 4; ++r)
            p[fn * 4 + r] = (kb + fn * 16 + r <= qpos) ? sfr[fn][r] * scale2 : NEG_INF;
      } else {
        #pragma unroll
        for (int fn = 0; fn < 4; ++fn)
          #pragma unroll
          for (int r = 0; r < 4; ++r)
            p[fn * 4 + r] = sfr[fn][r] * scale2;
      }
      float pmax = p[0];
      #pragma unroll
      for (int i = 1; i < 16; ++i) pmax = fmaxf(pmax, p[i]);
      pmax = fmaxf(pmax, __shfl_xor(pmax, 16));
      pmax = fmaxf(pmax, __shfl_xor(pmax, 32));
      if (!__all(pmax <= m + 8.0f)) {                 // defer-max (log2 units)
        float mn = fmaxf(m, pmax);
        float alpha = exp2a(m - mn);                  // MINIT-finite => never NaN
        m = mn; l *= alpha;
        #pragma unroll
        for (int r = 0; r < 4; ++r) {
          float aq = __shfl(alpha, q4 * 4 + r);       // group-0 lane holds q's stats
          #pragma unroll
          for (int db = 0; db < 8; ++db) o[db][r] *= aq;
        }
      }
      float rs = 0.f;
      #pragma unroll
      for (int i = 0; i < 16; ++i) { p[i] = exp2a(p[i] - m); rs += p[i]; }
      rs += __shfl_xor(rs, 16); rs += __shfl_xor(rs, 32);
      l += rs;
      // pack P: pf[w] slots j: kpos = j*64 + w*32 + (j>=4)*16 + 4*q4 + (j&3)
      s16x8 pf[2];
      #pragma unroll
      for (int w = 0; w < 2; ++w)
        #pragma unroll
        for (int i = 0; i < 8; ++i)
          pf[w][i] = (short)f2b(p[w * 8 + i]);
      // PV: V-frag with matching interleave, 2x b64 per (w, db)
      #pragma unroll
      for (int w = 0; w < 2; ++w) {
        const int cb = w * 32 + q4 * 4;
        #pragma unroll
        for (int db = 0; db < 8; ++db) {
          s16x4 va = *reinterpret_cast<const s16x4*>(&Vs[db * 16 + r16][cb]);
          s16x4 vb = *reinterpret_cast<const s16x4*>(&Vs[db * 16 + r16][cb + 16]);
          s16x8 vf = __builtin_shufflevector(va, vb, 0, 1, 2, 3, 4, 5, 6, 7);
          o[db] = __builtin_amdgcn_mfma_f32_16x16x32_bf16(pf[w], vf, o[db], 0, 0, 0);
        }
      }
    }
  }

  float rcpl = 1.0f / l;                              // valid at group-0 lanes
  float rlq[4];
  #pragma unroll
  for (int r = 0; r < 4; ++r) rlq[r] = __shfl(rcpl, q4 * 4 + r);
  #pragma unroll
  for (int db = 0; db < 8; ++db)
    #pragma unroll
    for (int r = 0; r < 4; ++r) {
      int t = qt * QB + wave * 16 + q4 * 4 + r;       // O lane map: q=4*q4+reg
      int d = db * 16 + r16;
      Y[(size_t)t * (HQ_ * HD_) + h * HD_ + d] = f2b(o[db][r] * rlq[r]);
    }
}

// ---------------------------------------------------------------------------
extern "C" void kernel_launch(void* const* d_in, const int* in_sizes, int n_in,
                              void* d_out, int out_size, void* d_ws, size_t ws_size,
                              hipStream_t stream) {
  const float* x  = (const float*)d_in[0];
  const float* wq = (const float*)d_in[1];
  const float* wk = (const float*)d_in[2];
  const float* wv = (const float*)d_in[3];
  const float* wo = (const float*)d_in[4];
  const float* fc = (const float*)d_in[5];
  const float* fs = (const float*)d_in[6];
  const float* kc = (const float*)d_in[7];
  const float* vc = (const float*)d_in[8];
  const int* ipos = (const int*)d_in[9];

  char* ws = (char*)d_ws;
  unsigned short* xb   = (unsigned short*)(ws);                 // [0, 12.58 MB)
  unsigned short* wqkv = (unsigned short*)(ws + 12582912);      // [12.58, 50.33)
  unsigned short* qkv  = (unsigned short*)(ws + 50331648);      // [50.33, 75.50) (later y)
  unsigned short* Qr   = (unsigned short*)(ws + 75497472);      // [75.50, 92.27)
  unsigned short* Kall = (unsigned short*)(ws + 92274688);      // [92.27, 100.66)
  unsigned short* VT   = (unsigned short*)(ws + 100663296);     // [100.66, 109.05)
  unsigned short* wo_b = (unsigned short*)(ws);                 // reuse region 0 after QKV GEMM
  unsigned short* y    = qkv;                                   // reuse after rope/vt

  // split-K partials: z=0 dead-wqkv [12.58, 37.75); z=1 dead Qr+Kall [75.50, 100.66)
  float* part0 = (float*)(ws + 12582912);
  float* part1 = (float*)(ws + 75497472);
  const int partStrideElems = (75497472 - 12582912) / 4;        // 15728640

  // converts: x, wq, wk, wv -> bf16
  k_cvt<<<6144, 256, 0, stream>>>(x, xb, 6291456 / 4);
  k_cvt<<<12288, 256, 0, stream>>>(wq, wqkv, 12582912 / 4);
  k_cvt<<<3072, 256, 0, stream>>>(wk, wqkv + 12582912, 3145728 / 4);
  k_cvt<<<3072, 256, 0, stream>>>(wv, wqkv + 15728640, 3145728 / 4);

  // fused QKV projection: qkv[2048][6144] = xb @ wqkv^T   (grid 8x24=192)
  k_gemm256<true><<<192, 512, 0, stream>>>(xb, wqkv, qkv, NQKV_, DIM_, 48, 24, 24, 0, 0);

  // wo -> bf16 (region 0 dead now)
  k_cvt<<<12288, 256, 0, stream>>>(wo, wo_b, 12582912 / 4);

  // RoPE + scatter + V transpose
  k_rope_q<<<16384, 256, 0, stream>>>(qkv, fc, fs, Qr);
  k_rope_k<<<4096, 256, 0, stream>>>(qkv, fc, fs, Kall, ipos);
  k_prefix<<<2048, 256, 0, stream>>>(kc, vc, Kall, VT, ipos);
  k_vt<<<256, 256, 0, stream>>>(qkv, VT, ipos);

  // attention -> y[2048][4096] (bf16)
  k_attn<<<1024, 256, 0, stream>>>(Qr, Kall, VT, y, ipos);

  // output projection, split-K=2: part[z] = y @ wo_b^T (K half each)
  k_gemm256<false><<<dim3(96, 2), 512, 0, stream>>>(y, wo_b, part0, DIM_, HQ_ * HD_,
                                                    32, 12, 12, 2048, partStrideElems);
  // reduce: out = part0 + part1
  k_add<<<1024, 256, 0, stream>>>((const f32x4*)part0, (const f32x4*)part1,
                                  (f32x4*)d_out, 6291456 / 4);
}

// Round 5
// 316.567 us; speedup vs baseline: 1.3390x; 1.0580x over previous
//
#include <hip/hip_runtime.h>
#include <hip/hip_bf16.h>
#include <stdint.h>

typedef float f32x4 __attribute__((ext_vector_type(4)));
typedef short s16x8 __attribute__((ext_vector_type(8)));
typedef short s16x4 __attribute__((ext_vector_type(4)));
typedef unsigned short u16x2 __attribute__((ext_vector_type(2)));
typedef unsigned short u16x4 __attribute__((ext_vector_type(4)));

#define AS1 __attribute__((address_space(1)))
#define AS3 __attribute__((address_space(3)))

static constexpr int T_    = 2048;
static constexpr int DIM_  = 3072;
static constexpr int HQ_   = 32;
static constexpr int HKV_  = 8;
static constexpr int HD_   = 128;
static constexpr int S_    = 4096;
static constexpr int NQKV_ = HQ_ * HD_ + 2 * HKV_ * HD_;   // 6144

__device__ __forceinline__ unsigned short f2b(float f) {
  return __builtin_bit_cast(unsigned short, __float2bfloat16(f));
}
__device__ __forceinline__ float b2f(unsigned short u) {
  return __bfloat162float(__builtin_bit_cast(__hip_bfloat16, u));
}
__device__ __forceinline__ float exp2a(float x) {      // exact v_exp_f32: 2^x
  float r; asm("v_exp_f32 %0, %1" : "=v"(r) : "v"(x)); return r;
}

__device__ __forceinline__ void gld_lds16(const void* g, void* l) {
  __builtin_amdgcn_global_load_lds((AS1 unsigned int*)(uintptr_t)g,
                                   (AS3 unsigned int*)l, 16, 0, 0);
}

#define FENCE() asm volatile("" ::: "memory")
#define BAR()   do { FENCE(); __builtin_amdgcn_s_barrier(); FENCE(); } while (0)
#define WAIT_LGKM0() asm volatile("s_waitcnt lgkmcnt(0)" ::: "memory")
#define WAIT_VM2()   asm volatile("s_waitcnt vmcnt(2)" ::: "memory")
#define WAIT_VM0()   asm volatile("s_waitcnt vmcnt(0)" ::: "memory")
#define SCHEDB()     __builtin_amdgcn_sched_barrier(0)

// ---------------- f32 -> bf16 convert ----------------
__global__ __launch_bounds__(256)
void k_cvt(const float* __restrict__ src, unsigned short* __restrict__ dst, int n4) {
  int i = blockIdx.x * 256 + threadIdx.x;
  if (i >= n4) return;
  float4 v = reinterpret_cast<const float4*>(src)[i];
  u16x4 o;
  o.x = f2b(v.x); o.y = f2b(v.y); o.z = f2b(v.z); o.w = f2b(v.w);
  reinterpret_cast<u16x4*>(dst)[i] = o;
}

// ---------------- 256x256 8-wave 4-phase NT GEMM (bf16 in) ------------------
// Read-once fragment schedule (24 ds_read_b128 / wave / K-tile):
//   P0: read afA(8)+bfA(4) -> MFMA (rows 0..63,  cols 0..31)
//   P1: read bfB(4)        -> MFMA (rows 0..63,  cols 32..63)  [afA reused]
//   P2: read afB(8)        -> MFMA (rows 64..127,cols 32..63)  [bfB reused]
//   P3: no reads           -> MFMA (rows 64..127,cols 0..31)   [bfA held from P0]
// Staging 2x gld_lds/phase; vmcnt(2) at P0/P3 only (counted, never 0 mid-loop).
template<bool OUT_BF16>
__global__ __launch_bounds__(512, 2)
void k_gemm256(const unsigned short* __restrict__ A,
               const unsigned short* __restrict__ B,
               void* __restrict__ Cout, int N, int K, int KT,
               int nbn, int xcdq, int k0step, int partStride) {
  __shared__ unsigned short lds_u[2][32768];           // 2 x 64 KiB
  char* ldsBase = (char*)&lds_u[0][0];

  const int bid = blockIdx.x;
  const int swz = (bid & 7) * xcdq + (bid >> 3);       // bijective: nwg % 8 == 0
  const int bm  = swz / nbn, bn = swz % nbn;
  const int tid = threadIdx.x, lane = tid & 63, wid = tid >> 6;
  const int wm  = wid >> 2, wn = wid & 3;
  const int r16 = lane & 15, q4 = lane >> 4;
  const int k0  = blockIdx.y * k0step;

  const unsigned short* Ag = A + (size_t)(bm * 256) * K + k0;
  const unsigned short* Bg = B + (size_t)(bn * 256) * K + k0;

  const int srow   = tid >> 3;                          // 0..63
  const int scol16 = (tid & 7) ^ (srow & 7);            // pre-swizzled source col
  const int scol   = scol16 * 8;                        // elements

  f32x4 acc[8][4] = {};                                 // acc[fi][fj], linear

  auto stageA = [&](int c, int r, int t) {
    gld_lds16(Ag + (size_t)(r * 64 + srow) * K + t * 64 + scol,
              ldsBase + c * 65536 + r * 8192 + tid * 16);
  };
  auto stageB = [&](int c, int r, int t) {
    gld_lds16(Bg + (size_t)(r * 64 + srow) * K + t * 64 + scol,
              ldsBase + c * 65536 + 32768 + r * 8192 + tid * 16);
  };
  auto stagePair = [&](int c, int pair, int t) {
    switch (pair) {
      case 0: stageB(c, 0, t); stageB(c, 1, t); break;
      case 1: stageB(c, 2, t); stageB(c, 3, t); break;
      case 2: stageA(c, 0, t); stageA(c, 2, t); break;
      case 3: stageA(c, 1, t); stageA(c, 3, t); break;
    }
  };

  // prologue: stage tile 0 into buf 0; leave A rounds 1,3 in flight (vm2)
  stagePair(0, 0, 0); stagePair(0, 1, 0); stagePair(0, 2, 0); stagePair(0, 3, 0);
  WAIT_VM2();
  BAR();

  for (int t = 0; t < KT; ++t) {
    const int  c = t & 1;
    const bool hasNext = (t + 1 < KT);
    char* base  = ldsBase + c * 65536;
    char* baseB = base + 32768;
    s16x8 afA[4][2], afB[4][2], bfA[2][2], bfB[2][2];

    // ---- P0: afA = A rows [wm*128, +64)  (round 2wm, complete);
    //          bfA = B rows [wn*64, +32)
    #pragma unroll
    for (int i = 0; i < 4; ++i) {
      const int arow = wm * 128 + i * 16 + r16;
      #pragma unroll
      for (int kk = 0; kk < 2; ++kk)
        afA[i][kk] = *(const s16x8*)(base + arow * 128 +
                                     (((kk * 4 + q4) ^ (arow & 7)) << 4));
    }
    #pragma unroll
    for (int j = 0; j < 2; ++j) {
      const int brow = wn * 64 + j * 16 + r16;
      #pragma unroll
      for (int kk = 0; kk < 2; ++kk)
        bfA[j][kk] = *(const s16x8*)(baseB + brow * 128 +
                                     (((kk * 4 + q4) ^ (brow & 7)) << 4));
    }
    if (hasNext) stagePair(c ^ 1, 0, t + 1);
    BAR();
    WAIT_LGKM0();
    SCHEDB();
    __builtin_amdgcn_s_setprio(1);
    #pragma unroll
    for (int i = 0; i < 4; ++i)
      #pragma unroll
      for (int j = 0; j < 2; ++j)
        #pragma unroll
        for (int kk = 0; kk < 2; ++kk)
          acc[i][j] = __builtin_amdgcn_mfma_f32_16x16x32_bf16(
              afA[i][kk], bfA[j][kk], acc[i][j], 0, 0, 0);
    __builtin_amdgcn_s_setprio(0);
    if (hasNext) WAIT_VM2(); else WAIT_VM0();   // A rounds 1,3 of tile t done
    BAR();

    // ---- P1: bfB = B rows [wn*64+32, +32)
    #pragma unroll
    for (int j = 0; j < 2; ++j) {
      const int brow = wn * 64 + 32 + j * 16 + r16;
      #pragma unroll
      for (int kk = 0; kk < 2; ++kk)
        bfB[j][kk] = *(const s16x8*)(baseB + brow * 128 +
                                     (((kk * 4 + q4) ^ (brow & 7)) << 4));
    }
    if (hasNext) stagePair(c ^ 1, 1, t + 1);
    BAR();
    WAIT_LGKM0();
    SCHEDB();
    __builtin_amdgcn_s_setprio(1);
    #pragma unroll
    for (int i = 0; i < 4; ++i)
      #pragma unroll
      for (int j = 0; j < 2; ++j)
        #pragma unroll
        for (int kk = 0; kk < 2; ++kk)
          acc[i][2 + j] = __builtin_amdgcn_mfma_f32_16x16x32_bf16(
              afA[i][kk], bfB[j][kk], acc[i][2 + j], 0, 0, 0);
    __builtin_amdgcn_s_setprio(0);
    BAR();

    // ---- P2: afB = A rows [wm*128+64, +64)  (round 2wm+1, waited at P0)
    #pragma unroll
    for (int i = 0; i < 4; ++i) {
      const int arow = wm * 128 + 64 + i * 16 + r16;
      #pragma unroll
      for (int kk = 0; kk < 2; ++kk)
        afB[i][kk] = *(const s16x8*)(base + arow * 128 +
                                     (((kk * 4 + q4) ^ (arow & 7)) << 4));
    }
    if (hasNext) stagePair(c ^ 1, 2, t + 1);
    BAR();
    WAIT_LGKM0();
    SCHEDB();
    __builtin_amdgcn_s_setprio(1);
    #pragma unroll
    for (int i = 0; i < 4; ++i)
      #pragma unroll
      for (int j = 0; j < 2; ++j)
        #pragma unroll
        for (int kk = 0; kk < 2; ++kk)
          acc[4 + i][2 + j] = __builtin_amdgcn_mfma_f32_16x16x32_bf16(
              afB[i][kk], bfB[j][kk], acc[4 + i][2 + j], 0, 0, 0);
    __builtin_amdgcn_s_setprio(0);
    BAR();

    // ---- P3: no LDS reads; bfA still live from P0
    if (hasNext) stagePair(c ^ 1, 3, t + 1);
    BAR();
    __builtin_amdgcn_s_setprio(1);
    #pragma unroll
    for (int i = 0; i < 4; ++i)
      #pragma unroll
      for (int j = 0; j < 2; ++j)
        #pragma unroll
        for (int kk = 0; kk < 2; ++kk)
          acc[4 + i][j] = __builtin_amdgcn_mfma_f32_16x16x32_bf16(
              afB[i][kk], bfA[j][kk], acc[4 + i][j], 0, 0, 0);
    __builtin_amdgcn_s_setprio(0);
    if (hasNext) WAIT_VM2();   // all of tile t+1 except A rounds 1,3
    BAR();
  }

  // epilogue: acc[fi][fj] -> rows wm*128+fi*16, cols wn*64+fj*16 (linear map)
  #pragma unroll
  for (int fi = 0; fi < 8; ++fi) {
    const int row = bm * 256 + wm * 128 + fi * 16 + q4 * 4;
    #pragma unroll
    for (int fj = 0; fj < 4; ++fj) {
      const int col = bn * 256 + wn * 64 + fj * 16 + r16;
      if constexpr (OUT_BF16) {
        unsigned short* C = (unsigned short*)Cout;
        #pragma unroll
        for (int rr = 0; rr < 4; ++rr)
          C[(size_t)(row + rr) * N + col] = f2b(acc[fi][fj][rr]);
      } else {
        float* C = (float*)Cout + (size_t)blockIdx.y * partStride;
        #pragma unroll
        for (int rr = 0; rr < 4; ++rr)
          C[(size_t)(row + rr) * N + col] = acc[fi][fj][rr];
      }
    }
  }
}

// ---------------- split-K reduce: out = p0 + p1 (f32) ----------------------
__global__ __launch_bounds__(256)
void k_add(const f32x4* __restrict__ a, const f32x4* __restrict__ b,
           f32x4* __restrict__ o, int n4) {
  int i = blockIdx.x * 256 + threadIdx.x;
  const int stride = gridDim.x * 256;
  for (; i < n4; i += stride) o[i] = a[i] + b[i];
}

// ---------------- RoPE on Q: qkv[t][h*128+d] -> Qr[h][t][d] ----------------
__global__ __launch_bounds__(256)
void k_rope_q(const unsigned short* __restrict__ qkv,
              const float* __restrict__ fc, const float* __restrict__ fs,
              unsigned short* __restrict__ Qr) {
  int idx = blockIdx.x * 256 + threadIdx.x;   // T*HQ*64
  int t   = idx >> 11;
  int rem = idx & 2047;
  int h   = rem >> 6;
  int d0  = (rem & 63) << 1;
  size_t qoff = (size_t)t * NQKV_ + h * HD_ + d0;
  u16x2 xv = *reinterpret_cast<const u16x2*>(&qkv[qoff]);
  float x0 = b2f(xv.x), x1 = b2f(xv.y);
  float c0 = fc[t * HD_ + d0], c1 = fc[t * HD_ + d0 + 1];
  float s0 = fs[t * HD_ + d0], s1 = fs[t * HD_ + d0 + 1];
  u16x2 o;
  o.x = f2b(x0 * c0 - x1 * s0);
  o.y = f2b(x1 * c1 + x0 * s1);
  *reinterpret_cast<u16x2*>(&Qr[((size_t)h * T_ + t) * HD_ + d0]) = o;
}

// ---------------- RoPE on K + scatter into Kall[hk][sp+t][d] ---------------
__global__ __launch_bounds__(256)
void k_rope_k(const unsigned short* __restrict__ qkv,
              const float* __restrict__ fc, const float* __restrict__ fs,
              unsigned short* __restrict__ Kall, const int* __restrict__ ipos) {
  int idx = blockIdx.x * 256 + threadIdx.x;   // T*HKV*64
  int t   = idx >> 9;
  int rem = idx & 511;
  int hk  = rem >> 6;
  int d0  = (rem & 63) << 1;
  int sp  = ipos[0];
  size_t qoff = (size_t)t * NQKV_ + HQ_ * HD_ + hk * HD_ + d0;
  u16x2 xv = *reinterpret_cast<const u16x2*>(&qkv[qoff]);
  float x0 = b2f(xv.x), x1 = b2f(xv.y);
  float c0 = fc[t * HD_ + d0], c1 = fc[t * HD_ + d0 + 1];
  float s0 = fs[t * HD_ + d0], s1 = fs[t * HD_ + d0 + 1];
  unsigned short o0 = f2b(x0 * c0 - x1 * s0);
  unsigned short o1 = f2b(x1 * c1 + x0 * s1);
  size_t ooff = ((size_t)hk * S_ + sp + t) * HD_ + d0;
  Kall[ooff] = o0; Kall[ooff + 1] = o1;
}

// ---------------- cache prefix (s < sp) into Kall / VT (grid-stride) -------
__global__ __launch_bounds__(256)
void k_prefix(const float* __restrict__ kc, const float* __restrict__ vc,
              unsigned short* __restrict__ Kall, unsigned short* __restrict__ VT,
              const int* __restrict__ ipos) {
  int sp = ipos[0];
  int total = sp * HKV_ * HD_;
  for (int idx = blockIdx.x * 256 + threadIdx.x; idx < total;
       idx += gridDim.x * 256) {
    int s   = idx >> 10;
    int rem = idx & 1023;
    int hk  = rem >> 7;
    int d   = rem & 127;
    Kall[((size_t)hk * S_ + s) * HD_ + d] = f2b(kc[((size_t)s * HKV_ + hk) * HD_ + d]);
    VT[((size_t)hk * HD_ + d) * S_ + s]   = f2b(vc[((size_t)s * HKV_ + hk) * HD_ + d]);
  }
}

// ---------------- V transpose: qkv v-section -> VT[hk][d][sp+t] ------------
__global__ __launch_bounds__(256)
void k_vt(const unsigned short* __restrict__ qkv,
          unsigned short* __restrict__ VT, const int* __restrict__ ipos) {
  int hk = blockIdx.x >> 5;     // 0..7
  int tt = blockIdx.x & 31;     // 0..31 (tiles of 64 t)
  int sp = ipos[0];
  __shared__ unsigned short lds[64][136];
  int tid = threadIdx.x;
  #pragma unroll
  for (int p = 0; p < 4; ++p) {
    int e   = p * 256 + tid;            // 0..1023
    int tr  = e >> 4;                   // 0..63
    int col = (e & 15) << 3;            // 0..120
    *reinterpret_cast<s16x8*>(&lds[tr][col]) =
        *reinterpret_cast<const s16x8*>(&qkv[(size_t)(tt * 64 + tr) * NQKV_ + (HQ_ + HKV_) * HD_ + hk * HD_ + col]);
  }
  __syncthreads();
  #pragma unroll
  for (int p = 0; p < 32; ++p) {
    int e = p * 256 + tid;              // 0..8191
    int d = e >> 6;                     // 0..127
    int t = e & 63;
    VT[((size_t)hk * HD_ + d) * S_ + sp + tt * 64 + t] = lds[t][d];
  }
}

// ---------------- flash attention v2: swapped QK^T, in-register softmax ----
__global__ __launch_bounds__(256, 4)
void k_attn(const unsigned short* __restrict__ Qr,
            const unsigned short* __restrict__ Kall,
            const unsigned short* __restrict__ VT,
            unsigned short* __restrict__ Y,
            const int* __restrict__ ipos) {
  constexpr int QB = 64, KB = 64;
  const int bid  = blockIdx.x;
  const int hk   = bid & 7;
  const int j2   = bid >> 3;
  const int h    = hk * 4 + (j2 & 3);
  const int qt   = j2 >> 2;
  const int sp   = ipos[0];
  const int tid  = threadIdx.x, lane = tid & 63, wave = tid >> 6;
  const int r16  = lane & 15, q4 = lane >> 4;
  const float NEG_INF = -__builtin_inff();
  const float MINIT   = -1.0e30f;          // finite init: avoids NaN in exp2 paths

  __shared__ unsigned short Ks[KB][HD_ + 8];      // 64 x 136
  __shared__ unsigned short Vs[HD_][KB + 8];      // 128 x 72

  const int qbase = qt * QB + wave * 16;
  s16x8 qf[4];
  const unsigned short* qp = Qr + ((size_t)h * T_ + qbase + r16) * HD_;
  #pragma unroll
  for (int ki = 0; ki < 4; ++ki)
    qf[ki] = *reinterpret_cast<const s16x8*>(qp + ki * 32 + q4 * 8);

  f32x4 o[8] = {};
  float m = MINIT, l = 0.f;
  const int qpos = sp + qbase + r16;              // this lane's softmax q-row
  const int qpos_wave_max = sp + qbase + 15;
  int jmax = (sp + qt * QB + QB - 1) >> 6;
  if (jmax > S_ / KB - 1) jmax = S_ / KB - 1;
  const float scale2 = 0.12751744416312068f;      // 1/sqrt(128) * log2(e)

  const unsigned short* Kbase = Kall + (size_t)hk * S_ * HD_;
  const unsigned short* Vbase = VT + (size_t)hk * HD_ * S_;

  for (int j = 0; j <= jmax; ++j) {
    s16x8 kreg[4], vreg[4];
    #pragma unroll
    for (int p = 0; p < 4; ++p) {
      int e  = p * 256 + tid;
      int kr = e >> 4, kc = (e & 15) << 3;
      kreg[p] = *reinterpret_cast<const s16x8*>(Kbase + (size_t)(j * KB + kr) * HD_ + kc);
      int vd = e >> 3, vs = (e & 7) << 3;
      vreg[p] = *reinterpret_cast<const s16x8*>(Vbase + (size_t)vd * S_ + j * KB + vs);
    }
    __syncthreads();
    #pragma unroll
    for (int p = 0; p < 4; ++p) {
      int e  = p * 256 + tid;
      int kr = e >> 4, kc = (e & 15) << 3;
      *reinterpret_cast<s16x8*>(&Ks[kr][kc]) = kreg[p];
      int vd = e >> 3, vs = (e & 7) << 3;
      *reinterpret_cast<s16x8*>(&Vs[vd][vs]) = vreg[p];
    }
    __syncthreads();

    const bool active = (j * KB <= qpos_wave_max);
    if (active) {
      // S^T = K Q^T : lane -> q=r16, kpos = j*64 + fn*16 + 4*q4 + reg
      f32x4 sfr[4];
      #pragma unroll
      for (int fn = 0; fn < 4; ++fn) {
        sfr[fn] = f32x4{0.f, 0.f, 0.f, 0.f};
        #pragma unroll
        for (int ki = 0; ki < 4; ++ki) {
          s16x8 kf = *reinterpret_cast<const s16x8*>(&Ks[fn * 16 + r16][ki * 32 + q4 * 8]);
          sfr[fn] = __builtin_amdgcn_mfma_f32_16x16x32_bf16(kf, qf[ki], sfr[fn], 0, 0, 0);
        }
      }
      float p[16];
      const bool needMask = (j * KB + KB - 1) > (sp + qbase);   // wave-uniform
      if (needMask) {
        const int kb = j * KB + q4 * 4;
        #pragma unroll
        for (int fn = 0; fn < 4; ++fn)
          #pragma unroll
          for (int r = 0; r < 4; ++r)
            p[fn * 4 + r] = (kb + fn * 16 + r <= qpos) ? sfr[fn][r] * scale2 : NEG_INF;
      } else {
        #pragma unroll
        for (int fn = 0; fn < 4; ++fn)
          #pragma unroll
          for (int r = 0; r < 4; ++r)
            p[fn * 4 + r] = sfr[fn][r] * scale2;
      }
      float pmax = p[0];
      #pragma unroll
      for (int i = 1; i < 16; ++i) pmax = fmaxf(pmax, p[i]);
      pmax = fmaxf(pmax, __shfl_xor(pmax, 16));
      pmax = fmaxf(pmax, __shfl_xor(pmax, 32));
      if (!__all(pmax <= m + 8.0f)) {                 // defer-max (log2 units)
        float mn = fmaxf(m, pmax);
        float alpha = exp2a(m - mn);                  // MINIT-finite => never NaN
        m = mn; l *= alpha;
        #pragma unroll
        for (int r = 0; r < 4; ++r) {
          float aq = __shfl(alpha, q4 * 4 + r);       // group-0 lane holds q's stats
          #pragma unroll
          for (int db = 0; db < 8; ++db) o[db][r] *= aq;
        }
      }
      float rs = 0.f;
      #pragma unroll
      for (int i = 0; i < 16; ++i) { p[i] = exp2a(p[i] - m); rs += p[i]; }
      rs += __shfl_xor(rs, 16); rs += __shfl_xor(rs, 32);
      l += rs;
      // pack P: pf[w] slots j: kpos = j*64 + w*32 + (j>=4)*16 + 4*q4 + (j&3)
      s16x8 pf[2];
      #pragma unroll
      for (int w = 0; w < 2; ++w)
        #pragma unroll
        for (int i = 0; i < 8; ++i)
          pf[w][i] = (short)f2b(p[w * 8 + i]);
      // PV: V-frag with matching interleave, 2x b64 per (w, db)
      #pragma unroll
      for (int w = 0; w < 2; ++w) {
        const int cb = w * 32 + q4 * 4;
        #pragma unroll
        for (int db = 0; db < 8; ++db) {
          s16x4 va = *reinterpret_cast<const s16x4*>(&Vs[db * 16 + r16][cb]);
          s16x4 vb = *reinterpret_cast<const s16x4*>(&Vs[db * 16 + r16][cb + 16]);
          s16x8 vf = __builtin_shufflevector(va, vb, 0, 1, 2, 3, 4, 5, 6, 7);
          o[db] = __builtin_amdgcn_mfma_f32_16x16x32_bf16(pf[w], vf, o[db], 0, 0, 0);
        }
      }
    }
  }

  float rcpl = 1.0f / l;                              // valid at group-0 lanes
  float rlq[4];
  #pragma unroll
  for (int r = 0; r < 4; ++r) rlq[r] = __shfl(rcpl, q4 * 4 + r);
  #pragma unroll
  for (int db = 0; db < 8; ++db)
    #pragma unroll
    for (int r = 0; r < 4; ++r) {
      int t = qt * QB + wave * 16 + q4 * 4 + r;       // O lane map: q=4*q4+reg
      int d = db * 16 + r16;
      Y[(size_t)t * (HQ_ * HD_) + h * HD_ + d] = f2b(o[db][r] * rlq[r]);
    }
}

// ---------------------------------------------------------------------------
extern "C" void kernel_launch(void* const* d_in, const int* in_sizes, int n_in,
                              void* d_out, int out_size, void* d_ws, size_t ws_size,
                              hipStream_t stream) {
  const float* x  = (const float*)d_in[0];
  const float* wq = (const float*)d_in[1];
  const float* wk = (const float*)d_in[2];
  const float* wv = (const float*)d_in[3];
  const float* wo = (const float*)d_in[4];
  const float* fc = (const float*)d_in[5];
  const float* fs = (const float*)d_in[6];
  const float* kc = (const float*)d_in[7];
  const float* vc = (const float*)d_in[8];
  const int* ipos = (const int*)d_in[9];

  char* ws = (char*)d_ws;
  unsigned short* xb   = (unsigned short*)(ws);                 // [0, 12.58 MB)
  unsigned short* wqkv = (unsigned short*)(ws + 12582912);      // [12.58, 50.33)
  unsigned short* qkv  = (unsigned short*)(ws + 50331648);      // [50.33, 75.50) (later y)
  unsigned short* Qr   = (unsigned short*)(ws + 75497472);      // [75.50, 92.27)
  unsigned short* Kall = (unsigned short*)(ws + 92274688);      // [92.27, 100.66)
  unsigned short* VT   = (unsigned short*)(ws + 100663296);     // [100.66, 109.05)
  unsigned short* wo_b = (unsigned short*)(ws);                 // reuse region 0 after QKV GEMM
  unsigned short* y    = qkv;                                   // reuse after rope/vt

  // split-K partials: z=0 dead-wqkv [12.58, 37.75); z=1 dead Qr+Kall [75.50, 100.66)
  float* part0 = (float*)(ws + 12582912);
  float* part1 = (float*)(ws + 75497472);
  const int partStrideElems = (75497472 - 12582912) / 4;        // 15728640

  // converts: x, wq, wk, wv -> bf16
  k_cvt<<<6144, 256, 0, stream>>>(x, xb, 6291456 / 4);
  k_cvt<<<12288, 256, 0, stream>>>(wq, wqkv, 12582912 / 4);
  k_cvt<<<3072, 256, 0, stream>>>(wk, wqkv + 12582912, 3145728 / 4);
  k_cvt<<<3072, 256, 0, stream>>>(wv, wqkv + 15728640, 3145728 / 4);

  // fused QKV projection: qkv[2048][6144] = xb @ wqkv^T   (grid 8x24=192)
  k_gemm256<true><<<192, 512, 0, stream>>>(xb, wqkv, qkv, NQKV_, DIM_, 48, 24, 24, 0, 0);

  // wo -> bf16 (region 0 dead now)
  k_cvt<<<12288, 256, 0, stream>>>(wo, wo_b, 12582912 / 4);

  // RoPE + scatter + V transpose
  k_rope_q<<<16384, 256, 0, stream>>>(qkv, fc, fs, Qr);
  k_rope_k<<<4096, 256, 0, stream>>>(qkv, fc, fs, Kall, ipos);
  k_prefix<<<2048, 256, 0, stream>>>(kc, vc, Kall, VT, ipos);
  k_vt<<<256, 256, 0, stream>>>(qkv, VT, ipos);

  // attention -> y[2048][4096] (bf16)
  k_attn<<<1024, 256, 0, stream>>>(Qr, Kall, VT, y, ipos);

  // output projection, split-K=2: part[z] = y @ wo_b^T (K half each)
  k_gemm256<false><<<dim3(96, 2), 512, 0, stream>>>(y, wo_b, part0, DIM_, HQ_ * HD_,
                                                    32, 12, 12, 2048, partStrideElems);
  // reduce: out = part0 + part1
  k_add<<<1024, 256, 0, stream>>>((const f32x4*)part0, (const f32x4*)part1,
                                  (f32x4*)d_out, 6291456 / 4);
}

// Round 6
// 304.675 us; speedup vs baseline: 1.3912x; 1.0390x over previous
//
#include <hip/hip_runtime.h>
#include <hip/hip_bf16.h>
#include <stdint.h>

typedef float f32x4 __attribute__((ext_vector_type(4)));
typedef short s16x8 __attribute__((ext_vector_type(8)));
typedef short s16x4 __attribute__((ext_vector_type(4)));
typedef unsigned short u16x2 __attribute__((ext_vector_type(2)));
typedef unsigned short u16x4 __attribute__((ext_vector_type(4)));

#define AS1 __attribute__((address_space(1)))
#define AS3 __attribute__((address_space(3)))

static constexpr int T_    = 2048;
static constexpr int DIM_  = 3072;
static constexpr int HQ_   = 32;
static constexpr int HKV_  = 8;
static constexpr int HD_   = 128;
static constexpr int S_    = 4096;
static constexpr int NQKV_ = HQ_ * HD_ + 2 * HKV_ * HD_;   // 6144

__device__ __forceinline__ unsigned short f2b(float f) {
  return __builtin_bit_cast(unsigned short, __float2bfloat16(f));
}
__device__ __forceinline__ float b2f(unsigned short u) {
  return __bfloat162float(__builtin_bit_cast(__hip_bfloat16, u));
}
__device__ __forceinline__ float exp2a(float x) {      // exact v_exp_f32: 2^x
  float r; asm("v_exp_f32 %0, %1" : "=v"(r) : "v"(x)); return r;
}

__device__ __forceinline__ void gld_lds16(const void* g, void* l) {
  __builtin_amdgcn_global_load_lds((AS1 unsigned int*)(uintptr_t)g,
                                   (AS3 unsigned int*)l, 16, 0, 0);
}

#define FENCE() asm volatile("" ::: "memory")
#define BAR()   do { FENCE(); __builtin_amdgcn_s_barrier(); FENCE(); } while (0)
#define WAIT_VM(n)   asm volatile("s_waitcnt vmcnt(" #n ")" ::: "memory")
#define WAIT_LGKM(n) asm volatile("s_waitcnt lgkmcnt(" #n ")" ::: "memory")
#define SCHEDB()     __builtin_amdgcn_sched_barrier(0)

// ---------------- f32 -> bf16 convert ----------------
__global__ __launch_bounds__(256)
void k_cvt(const float* __restrict__ src, unsigned short* __restrict__ dst, int n4) {
  int i = blockIdx.x * 256 + threadIdx.x;
  if (i >= n4) return;
  float4 v = reinterpret_cast<const float4*>(src)[i];
  u16x4 o;
  o.x = f2b(v.x); o.y = f2b(v.y); o.z = f2b(v.z); o.w = f2b(v.w);
  reinterpret_cast<u16x4*>(dst)[i] = o;
}

// ---------------- 256x256 8-wave 4-phase NT GEMM, pipelined reads -----------
// ds_reads at phase p feed MFMA at phase p+1 (counted lgkmcnt, never 0 on the
// MFMA path); gld_lds staged 2 phases ahead; every vmcnt targets loads >=3
// phases old. Reads/phase: P0 bfB(4), P1 afB(8), P2 none, P3 afA+bfA(12, next
// tile). MFMA: P0 Q00(afA*bfA) P1 Q01(afA*bfB) P2 Q10(afB*bfA) P3 Q11(afB*bfB).
// Stage slots: P0 pair2(t+1), P1 pair3(t+1), P2 pair0(t+2), P3 pair1(t+2).
// Steady vmcnt: P0=6, P2=4, P3=8. Tail t=KT-2: P2=2, P3=4. t=KT-1: P0=0.
template<bool OUT_BF16>
__global__ __launch_bounds__(512, 2)
void k_gemm256(const unsigned short* __restrict__ A,
               const unsigned short* __restrict__ B,
               void* __restrict__ Cout, int N, int K, int KT,
               int nbn, int xcdq, int k0step, int partStride) {
  __shared__ unsigned short lds_u[2][32768];           // 2 x 64 KiB
  char* ldsBase = (char*)&lds_u[0][0];

  const int bid = blockIdx.x;
  const int swz = (bid & 7) * xcdq + (bid >> 3);       // bijective: nwg % 8 == 0
  const int bm  = swz / nbn, bn = swz % nbn;
  const int tid = threadIdx.x, lane = tid & 63, wid = tid >> 6;
  const int wm  = wid >> 2, wn = wid & 3;
  const int r16 = lane & 15, q4 = lane >> 4;
  const int k0  = blockIdx.y * k0step;

  const unsigned short* Ag = A + (size_t)(bm * 256) * K + k0;
  const unsigned short* Bg = B + (size_t)(bn * 256) * K + k0;

  const int srow = tid >> 3;                            // 0..63
  const int scol = ((tid & 7) ^ (srow & 7)) * 8;        // pre-swizzled src col

  f32x4 acc[8][4] = {};
  s16x8 afA[4][2], afB[4][2], bfA[2][2], bfB[2][2];

  auto stageA = [&](int c, int r, int t) {
    gld_lds16(Ag + (size_t)(r * 64 + srow) * K + t * 64 + scol,
              ldsBase + c * 65536 + r * 8192 + tid * 16);
  };
  auto stageB = [&](int c, int r, int t) {
    gld_lds16(Bg + (size_t)(r * 64 + srow) * K + t * 64 + scol,
              ldsBase + c * 65536 + 32768 + r * 8192 + tid * 16);
  };
  auto stagePair = [&](int c, int pair, int t) {
    switch (pair) {
      case 0: stageB(c, 0, t); stageB(c, 1, t); break;   // B rows 0..127
      case 1: stageB(c, 2, t); stageB(c, 3, t); break;   // B rows 128..255
      case 2: stageA(c, 0, t); stageA(c, 2, t); break;   // A rows 0..63,128..191
      case 3: stageA(c, 1, t); stageA(c, 3, t); break;   // A rows 64..127,192..255
    }
  };
  auto readAF = [&](s16x8 (&dst)[4][2], char* base, int rowoff) {
    #pragma unroll
    for (int i = 0; i < 4; ++i) {
      const int arow = wm * 128 + rowoff + i * 16 + r16;
      #pragma unroll
      for (int kk = 0; kk < 2; ++kk)
        dst[i][kk] = *(const s16x8*)(base + arow * 128 +
                                     (((kk * 4 + q4) ^ (arow & 7)) << 4));
    }
  };
  auto readBF = [&](s16x8 (&dst)[2][2], char* base, int rowoff) {
    #pragma unroll
    for (int j = 0; j < 2; ++j) {
      const int brow = wn * 64 + rowoff + j * 16 + r16;
      #pragma unroll
      for (int kk = 0; kk < 2; ++kk)
        dst[j][kk] = *(const s16x8*)(base + 32768 + brow * 128 +
                                     (((kk * 4 + q4) ^ (brow & 7)) << 4));
    }
  };

#define MFMA16(AF, BF, IO, JO)                                                 \
  __builtin_amdgcn_s_setprio(1);                                               \
  _Pragma("unroll")                                                            \
  for (int i_ = 0; i_ < 4; ++i_) {                                             \
    _Pragma("unroll")                                                          \
    for (int j_ = 0; j_ < 2; ++j_) {                                           \
      _Pragma("unroll")                                                        \
      for (int kk_ = 0; kk_ < 2; ++kk_)                                        \
        acc[(IO) + i_][(JO) + j_] = __builtin_amdgcn_mfma_f32_16x16x32_bf16(   \
            AF[i_][kk_], BF[j_][kk_], acc[(IO) + i_][(JO) + j_], 0, 0, 0);     \
    }                                                                          \
  }                                                                            \
  __builtin_amdgcn_s_setprio(0);

  // ---- prologue: stage tile0 (4 pairs) + tile1 pairs 0,1 ; pre-read Q00 ----
  stagePair(0, 0, 0); stagePair(0, 1, 0); stagePair(0, 2, 0); stagePair(0, 3, 0);
  stagePair(1, 0, 1); stagePair(1, 1, 1);
  WAIT_VM(6);                 // pairs 0,1,2 of tile0 landed
  BAR();
  readAF(afA, ldsBase, 0);
  readBF(bfA, ldsBase, 0);

  // ---- main loop: t in [0, KT-2) ----
  for (int t = 0; t < KT - 2; ++t) {
    const int c = t & 1;
    char* baseC = ldsBase + c * 65536;
    char* baseN = ldsBase + (c ^ 1) * 65536;
    // P0
    readBF(bfB, baseC, 32);
    stagePair(c ^ 1, 2, t + 1);
    WAIT_VM(6); BAR();
    WAIT_LGKM(4); SCHEDB();
    MFMA16(afA, bfA, 0, 0);
    BAR();
    // P1
    readAF(afB, baseC, 64);
    stagePair(c ^ 1, 3, t + 1);
    BAR();
    WAIT_LGKM(8); SCHEDB();
    MFMA16(afA, bfB, 0, 2);
    BAR();
    // P2
    stagePair(c, 0, t + 2);
    WAIT_VM(4); BAR();
    WAIT_LGKM(0); SCHEDB();
    MFMA16(afB, bfA, 4, 0);
    BAR();
    // P3 (reads next tile's Q00 operands)
    readAF(afA, baseN, 0);
    readBF(bfA, baseN, 0);
    stagePair(c, 1, t + 2);
    WAIT_VM(8); BAR();
    WAIT_LGKM(12); SCHEDB();
    MFMA16(afB, bfB, 4, 2);
    BAR();
  }

  // ---- tile KT-2 (no t+2 staging; adjusted vmcnt) ----
  {
    const int t = KT - 2;
    const int c = t & 1;
    char* baseC = ldsBase + c * 65536;
    char* baseN = ldsBase + (c ^ 1) * 65536;
    readBF(bfB, baseC, 32);
    stagePair(c ^ 1, 2, t + 1);
    WAIT_VM(6); BAR();
    WAIT_LGKM(4); SCHEDB();
    MFMA16(afA, bfA, 0, 0);
    BAR();
    readAF(afB, baseC, 64);
    stagePair(c ^ 1, 3, t + 1);
    BAR();
    WAIT_LGKM(8); SCHEDB();
    MFMA16(afA, bfB, 0, 2);
    BAR();
    WAIT_VM(2); BAR();
    WAIT_LGKM(0); SCHEDB();
    MFMA16(afB, bfA, 4, 0);
    BAR();
    readAF(afA, baseN, 0);
    readBF(bfA, baseN, 0);
    WAIT_VM(4); BAR();
    WAIT_LGKM(12); SCHEDB();
    MFMA16(afB, bfB, 4, 2);
    BAR();
  }
  // ---- tile KT-1 (no staging, no next reads) ----
  {
    const int t = KT - 1;
    char* baseC = ldsBase + (t & 1) * 65536;
    readBF(bfB, baseC, 32);
    WAIT_VM(0); BAR();
    WAIT_LGKM(4); SCHEDB();
    MFMA16(afA, bfA, 0, 0);
    BAR();
    readAF(afB, baseC, 64);
    BAR();
    WAIT_LGKM(8); SCHEDB();
    MFMA16(afA, bfB, 0, 2);
    BAR();
    WAIT_LGKM(0); SCHEDB();
    MFMA16(afB, bfA, 4, 0);
    MFMA16(afB, bfB, 4, 2);
  }
#undef MFMA16

  // epilogue: acc[fi][fj] -> rows wm*128+fi*16, cols wn*64+fj*16
  #pragma unroll
  for (int fi = 0; fi < 8; ++fi) {
    const int row = bm * 256 + wm * 128 + fi * 16 + q4 * 4;
    #pragma unroll
    for (int fj = 0; fj < 4; ++fj) {
      const int col = bn * 256 + wn * 64 + fj * 16 + r16;
      if constexpr (OUT_BF16) {
        unsigned short* C = (unsigned short*)Cout;
        #pragma unroll
        for (int rr = 0; rr < 4; ++rr)
          C[(size_t)(row + rr) * N + col] = f2b(acc[fi][fj][rr]);
      } else {
        float* C = (float*)Cout + (size_t)blockIdx.y * partStride;
        #pragma unroll
        for (int rr = 0; rr < 4; ++rr)
          C[(size_t)(row + rr) * N + col] = acc[fi][fj][rr];
      }
    }
  }
}

// ---------------- split-K reduce: out = p0 + p1 (f32) ----------------------
__global__ __launch_bounds__(256)
void k_add(const f32x4* __restrict__ a, const f32x4* __restrict__ b,
           f32x4* __restrict__ o, int n4) {
  int i = blockIdx.x * 256 + threadIdx.x;
  const int stride = gridDim.x * 256;
  for (; i < n4; i += stride) o[i] = a[i] + b[i];
}

// ---------------- RoPE on Q: qkv[t][h*128+d] -> Qr[h][t][d] ----------------
__global__ __launch_bounds__(256)
void k_rope_q(const unsigned short* __restrict__ qkv,
              const float* __restrict__ fc, const float* __restrict__ fs,
              unsigned short* __restrict__ Qr) {
  int idx = blockIdx.x * 256 + threadIdx.x;   // T*HQ*64
  int t   = idx >> 11;
  int rem = idx & 2047;
  int h   = rem >> 6;
  int d0  = (rem & 63) << 1;
  size_t qoff = (size_t)t * NQKV_ + h * HD_ + d0;
  u16x2 xv = *reinterpret_cast<const u16x2*>(&qkv[qoff]);
  float x0 = b2f(xv.x), x1 = b2f(xv.y);
  float c0 = fc[t * HD_ + d0], c1 = fc[t * HD_ + d0 + 1];
  float s0 = fs[t * HD_ + d0], s1 = fs[t * HD_ + d0 + 1];
  u16x2 o;
  o.x = f2b(x0 * c0 - x1 * s0);
  o.y = f2b(x1 * c1 + x0 * s1);
  *reinterpret_cast<u16x2*>(&Qr[((size_t)h * T_ + t) * HD_ + d0]) = o;
}

// ---------------- RoPE on K + scatter into Kall[hk][sp+t][d] ---------------
__global__ __launch_bounds__(256)
void k_rope_k(const unsigned short* __restrict__ qkv,
              const float* __restrict__ fc, const float* __restrict__ fs,
              unsigned short* __restrict__ Kall, const int* __restrict__ ipos) {
  int idx = blockIdx.x * 256 + threadIdx.x;   // T*HKV*64
  int t   = idx >> 9;
  int rem = idx & 511;
  int hk  = rem >> 6;
  int d0  = (rem & 63) << 1;
  int sp  = ipos[0];
  size_t qoff = (size_t)t * NQKV_ + HQ_ * HD_ + hk * HD_ + d0;
  u16x2 xv = *reinterpret_cast<const u16x2*>(&qkv[qoff]);
  float x0 = b2f(xv.x), x1 = b2f(xv.y);
  float c0 = fc[t * HD_ + d0], c1 = fc[t * HD_ + d0 + 1];
  float s0 = fs[t * HD_ + d0], s1 = fs[t * HD_ + d0 + 1];
  unsigned short o0 = f2b(x0 * c0 - x1 * s0);
  unsigned short o1 = f2b(x1 * c1 + x0 * s1);
  size_t ooff = ((size_t)hk * S_ + sp + t) * HD_ + d0;
  Kall[ooff] = o0; Kall[ooff + 1] = o1;
}

// ---------------- cache prefix (s < sp) into Kall / VT (grid-stride) -------
__global__ __launch_bounds__(256)
void k_prefix(const float* __restrict__ kc, const float* __restrict__ vc,
              unsigned short* __restrict__ Kall, unsigned short* __restrict__ VT,
              const int* __restrict__ ipos) {
  int sp = ipos[0];
  int total = sp * HKV_ * HD_;
  for (int idx = blockIdx.x * 256 + threadIdx.x; idx < total;
       idx += gridDim.x * 256) {
    int s   = idx >> 10;
    int rem = idx & 1023;
    int hk  = rem >> 7;
    int d   = rem & 127;
    Kall[((size_t)hk * S_ + s) * HD_ + d] = f2b(kc[((size_t)s * HKV_ + hk) * HD_ + d]);
    VT[((size_t)hk * HD_ + d) * S_ + s]   = f2b(vc[((size_t)s * HKV_ + hk) * HD_ + d]);
  }
}

// ---------------- V transpose: qkv v-section -> VT[hk][d][sp+t] ------------
__global__ __launch_bounds__(256)
void k_vt(const unsigned short* __restrict__ qkv,
          unsigned short* __restrict__ VT, const int* __restrict__ ipos) {
  int hk = blockIdx.x >> 5;     // 0..7
  int tt = blockIdx.x & 31;     // 0..31 (tiles of 64 t)
  int sp = ipos[0];
  __shared__ unsigned short lds[64][136];
  int tid = threadIdx.x;
  #pragma unroll
  for (int p = 0; p < 4; ++p) {
    int e   = p * 256 + tid;            // 0..1023
    int tr  = e >> 4;                   // 0..63
    int col = (e & 15) << 3;            // 0..120
    *reinterpret_cast<s16x8*>(&lds[tr][col]) =
        *reinterpret_cast<const s16x8*>(&qkv[(size_t)(tt * 64 + tr) * NQKV_ + (HQ_ + HKV_) * HD_ + hk * HD_ + col]);
  }
  __syncthreads();
  #pragma unroll
  for (int p = 0; p < 32; ++p) {
    int e = p * 256 + tid;              // 0..8191
    int d = e >> 6;                     // 0..127
    int t = e & 63;
    VT[((size_t)hk * HD_ + d) * S_ + sp + tt * 64 + t] = lds[t][d];
  }
}

// ---------------- flash attention v2: swapped QK^T, in-register softmax ----
__global__ __launch_bounds__(256, 4)
void k_attn(const unsigned short* __restrict__ Qr,
            const unsigned short* __restrict__ Kall,
            const unsigned short* __restrict__ VT,
            unsigned short* __restrict__ Y,
            const int* __restrict__ ipos) {
  constexpr int QB = 64, KB = 64;
  const int bid  = blockIdx.x;
  const int hk   = bid & 7;
  const int j2   = bid >> 3;
  const int h    = hk * 4 + (j2 & 3);
  const int qt   = j2 >> 2;
  const int sp   = ipos[0];
  const int tid  = threadIdx.x, lane = tid & 63, wave = tid >> 6;
  const int r16  = lane & 15, q4 = lane >> 4;
  const float NEG_INF = -__builtin_inff();
  const float MINIT   = -1.0e30f;          // finite init: avoids NaN in exp2 paths

  __shared__ unsigned short Ks[KB][HD_ + 8];      // 64 x 136
  __shared__ unsigned short Vs[HD_][KB + 8];      // 128 x 72

  const int qbase = qt * QB + wave * 16;
  s16x8 qf[4];
  const unsigned short* qp = Qr + ((size_t)h * T_ + qbase + r16) * HD_;
  #pragma unroll
  for (int ki = 0; ki < 4; ++ki)
    qf[ki] = *reinterpret_cast<const s16x8*>(qp + ki * 32 + q4 * 8);

  f32x4 o[8] = {};
  float m = MINIT, l = 0.f;
  const int qpos = sp + qbase + r16;              // this lane's softmax q-row
  const int qpos_wave_max = sp + qbase + 15;
  int jmax = (sp + qt * QB + QB - 1) >> 6;
  if (jmax > S_ / KB - 1) jmax = S_ / KB - 1;
  const float scale2 = 0.12751744416312068f;      // 1/sqrt(128) * log2(e)

  const unsigned short* Kbase = Kall + (size_t)hk * S_ * HD_;
  const unsigned short* Vbase = VT + (size_t)hk * HD_ * S_;

  for (int j = 0; j <= jmax; ++j) {
    s16x8 kreg[4], vreg[4];
    #pragma unroll
    for (int p = 0; p < 4; ++p) {
      int e  = p * 256 + tid;
      int kr = e >> 4, kc = (e & 15) << 3;
      kreg[p] = *reinterpret_cast<const s16x8*>(Kbase + (size_t)(j * KB + kr) * HD_ + kc);
      int vd = e >> 3, vs = (e & 7) << 3;
      vreg[p] = *reinterpret_cast<const s16x8*>(Vbase + (size_t)vd * S_ + j * KB + vs);
    }
    __syncthreads();
    #pragma unroll
    for (int p = 0; p < 4; ++p) {
      int e  = p * 256 + tid;
      int kr = e >> 4, kc = (e & 15) << 3;
      *reinterpret_cast<s16x8*>(&Ks[kr][kc]) = kreg[p];
      int vd = e >> 3, vs = (e & 7) << 3;
      *reinterpret_cast<s16x8*>(&Vs[vd][vs]) = vreg[p];
    }
    __syncthreads();

    const bool active = (j * KB <= qpos_wave_max);
    if (active) {
      // S^T = K Q^T : lane -> q=r16, kpos = j*64 + fn*16 + 4*q4 + reg
      f32x4 sfr[4];
      #pragma unroll
      for (int fn = 0; fn < 4; ++fn) {
        sfr[fn] = f32x4{0.f, 0.f, 0.f, 0.f};
        #pragma unroll
        for (int ki = 0; ki < 4; ++ki) {
          s16x8 kf = *reinterpret_cast<const s16x8*>(&Ks[fn * 16 + r16][ki * 32 + q4 * 8]);
          sfr[fn] = __builtin_amdgcn_mfma_f32_16x16x32_bf16(kf, qf[ki], sfr[fn], 0, 0, 0);
        }
      }
      float p[16];
      const bool needMask = (j * KB + KB - 1) > (sp + qbase);   // wave-uniform
      if (needMask) {
        const int kb = j * KB + q4 * 4;
        #pragma unroll
        for (int fn = 0; fn < 4; ++fn)
          #pragma unroll
          for (int r = 0; r < 4; ++r)
            p[fn * 4 + r] = (kb + fn * 16 + r <= qpos) ? sfr[fn][r] * scale2 : NEG_INF;
      } else {
        #pragma unroll
        for (int fn = 0; fn < 4; ++fn)
          #pragma unroll
          for (int r = 0; r < 4; ++r)
            p[fn * 4 + r] = sfr[fn][r] * scale2;
      }
      float pmax = p[0];
      #pragma unroll
      for (int i = 1; i < 16; ++i) pmax = fmaxf(pmax, p[i]);
      pmax = fmaxf(pmax, __shfl_xor(pmax, 16));
      pmax = fmaxf(pmax, __shfl_xor(pmax, 32));
      if (!__all(pmax <= m + 8.0f)) {                 // defer-max (log2 units)
        float mn = fmaxf(m, pmax);
        float alpha = exp2a(m - mn);                  // MINIT-finite => never NaN
        m = mn; l *= alpha;
        #pragma unroll
        for (int r = 0; r < 4; ++r) {
          float aq = __shfl(alpha, q4 * 4 + r);       // group-0 lane holds q's stats
          #pragma unroll
          for (int db = 0; db < 8; ++db) o[db][r] *= aq;
        }
      }
      float rs = 0.f;
      #pragma unroll
      for (int i = 0; i < 16; ++i) { p[i] = exp2a(p[i] - m); rs += p[i]; }
      rs += __shfl_xor(rs, 16); rs += __shfl_xor(rs, 32);
      l += rs;
      // pack P: pf[w] slots j: kpos = j*64 + w*32 + (j>=4)*16 + 4*q4 + (j&3)
      s16x8 pf[2];
      #pragma unroll
      for (int w = 0; w < 2; ++w)
        #pragma unroll
        for (int i = 0; i < 8; ++i)
          pf[w][i] = (short)f2b(p[w * 8 + i]);
      // PV: V-frag with matching interleave, 2x b64 per (w, db)
      #pragma unroll
      for (int w = 0; w < 2; ++w) {
        const int cb = w * 32 + q4 * 4;
        #pragma unroll
        for (int db = 0; db < 8; ++db) {
          s16x4 va = *reinterpret_cast<const s16x4*>(&Vs[db * 16 + r16][cb]);
          s16x4 vb = *reinterpret_cast<const s16x4*>(&Vs[db * 16 + r16][cb + 16]);
          s16x8 vf = __builtin_shufflevector(va, vb, 0, 1, 2, 3, 4, 5, 6, 7);
          o[db] = __builtin_amdgcn_mfma_f32_16x16x32_bf16(pf[w], vf, o[db], 0, 0, 0);
        }
      }
    }
  }

  float rcpl = 1.0f / l;                              // valid at group-0 lanes
  float rlq[4];
  #pragma unroll
  for (int r = 0; r < 4; ++r) rlq[r] = __shfl(rcpl, q4 * 4 + r);
  #pragma unroll
  for (int db = 0; db < 8; ++db)
    #pragma unroll
    for (int r = 0; r < 4; ++r) {
      int t = qt * QB + wave * 16 + q4 * 4 + r;       // O lane map: q=4*q4+reg
      int d = db * 16 + r16;
      Y[(size_t)t * (HQ_ * HD_) + h * HD_ + d] = f2b(o[db][r] * rlq[r]);
    }
}

// ---------------------------------------------------------------------------
extern "C" void kernel_launch(void* const* d_in, const int* in_sizes, int n_in,
                              void* d_out, int out_size, void* d_ws, size_t ws_size,
                              hipStream_t stream) {
  const float* x  = (const float*)d_in[0];
  const float* wq = (const float*)d_in[1];
  const float* wk = (const float*)d_in[2];
  const float* wv = (const float*)d_in[3];
  const float* wo = (const float*)d_in[4];
  const float* fc = (const float*)d_in[5];
  const float* fs = (const float*)d_in[6];
  const float* kc = (const float*)d_in[7];
  const float* vc = (const float*)d_in[8];
  const int* ipos = (const int*)d_in[9];

  char* ws = (char*)d_ws;
  unsigned short* xb   = (unsigned short*)(ws);                 // [0, 12.58 MB)
  unsigned short* wqkv = (unsigned short*)(ws + 12582912);      // [12.58, 50.33)
  unsigned short* qkv  = (unsigned short*)(ws + 50331648);      // [50.33, 75.50) (later y)
  unsigned short* Qr   = (unsigned short*)(ws + 75497472);      // [75.50, 92.27)
  unsigned short* Kall = (unsigned short*)(ws + 92274688);      // [92.27, 100.66)
  unsigned short* VT   = (unsigned short*)(ws + 100663296);     // [100.66, 109.05)
  unsigned short* wo_b = (unsigned short*)(ws);                 // reuse region 0 after QKV GEMM
  unsigned short* y    = qkv;                                   // reuse after rope/vt

  // split-K partials: z=0 dead-wqkv [12.58, 37.75); z=1 dead Qr+Kall [75.50, 100.66)
  float* part0 = (float*)(ws + 12582912);
  float* part1 = (float*)(ws + 75497472);
  const int partStrideElems = (75497472 - 12582912) / 4;        // 15728640

  // converts: x, wq, wk, wv -> bf16
  k_cvt<<<6144, 256, 0, stream>>>(x, xb, 6291456 / 4);
  k_cvt<<<12288, 256, 0, stream>>>(wq, wqkv, 12582912 / 4);
  k_cvt<<<3072, 256, 0, stream>>>(wk, wqkv + 12582912, 3145728 / 4);
  k_cvt<<<3072, 256, 0, stream>>>(wv, wqkv + 15728640, 3145728 / 4);

  // fused QKV projection: qkv[2048][6144] = xb @ wqkv^T   (grid 8x24=192)
  k_gemm256<true><<<192, 512, 0, stream>>>(xb, wqkv, qkv, NQKV_, DIM_, 48, 24, 24, 0, 0);

  // wo -> bf16 (region 0 dead now)
  k_cvt<<<12288, 256, 0, stream>>>(wo, wo_b, 12582912 / 4);

  // RoPE + scatter + V transpose
  k_rope_q<<<16384, 256, 0, stream>>>(qkv, fc, fs, Qr);
  k_rope_k<<<4096, 256, 0, stream>>>(qkv, fc, fs, Kall, ipos);
  k_prefix<<<2048, 256, 0, stream>>>(kc, vc, Kall, VT, ipos);
  k_vt<<<256, 256, 0, stream>>>(qkv, VT, ipos);

  // attention -> y[2048][4096] (bf16)
  k_attn<<<1024, 256, 0, stream>>>(Qr, Kall, VT, y, ipos);

  // output projection, split-K=2: part[z] = y @ wo_b^T (K half each)
  k_gemm256<false><<<dim3(96, 2), 512, 0, stream>>>(y, wo_b, part0, DIM_, HQ_ * HD_,
                                                    32, 12, 12, 2048, partStrideElems);
  // reduce: out = part0 + part1
  k_add<<<1024, 256, 0, stream>>>((const f32x4*)part0, (const f32x4*)part1,
                                  (f32x4*)d_out, 6291456 / 4);
}

// Round 7
// 287.271 us; speedup vs baseline: 1.4755x; 1.0606x over previous
//
#include <hip/hip_runtime.h>
#include <hip/hip_bf16.h>
#include <stdint.h>

typedef float f32x4 __attribute__((ext_vector_type(4)));
typedef short s16x8 __attribute__((ext_vector_type(8)));
typedef short s16x4 __attribute__((ext_vector_type(4)));
typedef unsigned short u16x2 __attribute__((ext_vector_type(2)));
typedef unsigned short u16x4 __attribute__((ext_vector_type(4)));

#define AS1 __attribute__((address_space(1)))
#define AS3 __attribute__((address_space(3)))

static constexpr int T_    = 2048;
static constexpr int DIM_  = 3072;
static constexpr int HQ_   = 32;
static constexpr int HKV_  = 8;
static constexpr int HD_   = 128;
static constexpr int S_    = 4096;
static constexpr int NQKV_ = HQ_ * HD_ + 2 * HKV_ * HD_;   // 6144

__device__ __forceinline__ unsigned short f2b(float f) {
  return __builtin_bit_cast(unsigned short, __float2bfloat16(f));
}
__device__ __forceinline__ float b2f(unsigned short u) {
  return __bfloat162float(__builtin_bit_cast(__hip_bfloat16, u));
}
__device__ __forceinline__ float exp2a(float x) {      // exact v_exp_f32: 2^x
  float r; asm("v_exp_f32 %0, %1" : "=v"(r) : "v"(x)); return r;
}

__device__ __forceinline__ void gld_lds16(const void* g, void* l) {
  __builtin_amdgcn_global_load_lds((AS1 unsigned int*)(uintptr_t)g,
                                   (AS3 unsigned int*)l, 16, 0, 0);
}

#define FENCE() asm volatile("" ::: "memory")
#define BAR()   do { FENCE(); __builtin_amdgcn_s_barrier(); FENCE(); } while (0)
#define WAIT_VM(n)   asm volatile("s_waitcnt vmcnt(" #n ")" ::: "memory")
#define WAIT_LGKM(n) asm volatile("s_waitcnt lgkmcnt(" #n ")" ::: "memory")
#define SCHEDB()     __builtin_amdgcn_sched_barrier(0)

// ---------------- f32 -> bf16 convert ----------------
__global__ __launch_bounds__(256)
void k_cvt(const float* __restrict__ src, unsigned short* __restrict__ dst, int n4) {
  int i = blockIdx.x * 256 + threadIdx.x;
  if (i >= n4) return;
  float4 v = reinterpret_cast<const float4*>(src)[i];
  u16x4 o;
  o.x = f2b(v.x); o.y = f2b(v.y); o.z = f2b(v.z); o.w = f2b(v.w);
  reinterpret_cast<u16x4*>(dst)[i] = o;
}

// ---------------- 256x256 8-wave 4-phase NT GEMM, pipelined reads -----------
// (unchanged from round 6 — verified)
template<bool OUT_BF16>
__global__ __launch_bounds__(512, 2)
void k_gemm256(const unsigned short* __restrict__ A,
               const unsigned short* __restrict__ B,
               void* __restrict__ Cout, int N, int K, int KT,
               int nbn, int xcdq, int k0step, int partStride) {
  __shared__ unsigned short lds_u[2][32768];           // 2 x 64 KiB
  char* ldsBase = (char*)&lds_u[0][0];

  const int bid = blockIdx.x;
  const int swz = (bid & 7) * xcdq + (bid >> 3);       // bijective: nwg % 8 == 0
  const int bm  = swz / nbn, bn = swz % nbn;
  const int tid = threadIdx.x, lane = tid & 63, wid = tid >> 6;
  const int wm  = wid >> 2, wn = wid & 3;
  const int r16 = lane & 15, q4 = lane >> 4;
  const int k0  = blockIdx.y * k0step;

  const unsigned short* Ag = A + (size_t)(bm * 256) * K + k0;
  const unsigned short* Bg = B + (size_t)(bn * 256) * K + k0;

  const int srow = tid >> 3;                            // 0..63
  const int scol = ((tid & 7) ^ (srow & 7)) * 8;        // pre-swizzled src col

  f32x4 acc[8][4] = {};
  s16x8 afA[4][2], afB[4][2], bfA[2][2], bfB[2][2];

  auto stageA = [&](int c, int r, int t) {
    gld_lds16(Ag + (size_t)(r * 64 + srow) * K + t * 64 + scol,
              ldsBase + c * 65536 + r * 8192 + tid * 16);
  };
  auto stageB = [&](int c, int r, int t) {
    gld_lds16(Bg + (size_t)(r * 64 + srow) * K + t * 64 + scol,
              ldsBase + c * 65536 + 32768 + r * 8192 + tid * 16);
  };
  auto stagePair = [&](int c, int pair, int t) {
    switch (pair) {
      case 0: stageB(c, 0, t); stageB(c, 1, t); break;   // B rows 0..127
      case 1: stageB(c, 2, t); stageB(c, 3, t); break;   // B rows 128..255
      case 2: stageA(c, 0, t); stageA(c, 2, t); break;   // A rows 0..63,128..191
      case 3: stageA(c, 1, t); stageA(c, 3, t); break;   // A rows 64..127,192..255
    }
  };
  auto readAF = [&](s16x8 (&dst)[4][2], char* base, int rowoff) {
    #pragma unroll
    for (int i = 0; i < 4; ++i) {
      const int arow = wm * 128 + rowoff + i * 16 + r16;
      #pragma unroll
      for (int kk = 0; kk < 2; ++kk)
        dst[i][kk] = *(const s16x8*)(base + arow * 128 +
                                     (((kk * 4 + q4) ^ (arow & 7)) << 4));
    }
  };
  auto readBF = [&](s16x8 (&dst)[2][2], char* base, int rowoff) {
    #pragma unroll
    for (int j = 0; j < 2; ++j) {
      const int brow = wn * 64 + rowoff + j * 16 + r16;
      #pragma unroll
      for (int kk = 0; kk < 2; ++kk)
        dst[j][kk] = *(const s16x8*)(base + 32768 + brow * 128 +
                                     (((kk * 4 + q4) ^ (brow & 7)) << 4));
    }
  };

#define MFMA16(AF, BF, IO, JO)                                                 \
  __builtin_amdgcn_s_setprio(1);                                               \
  _Pragma("unroll")                                                            \
  for (int i_ = 0; i_ < 4; ++i_) {                                             \
    _Pragma("unroll")                                                          \
    for (int j_ = 0; j_ < 2; ++j_) {                                           \
      _Pragma("unroll")                                                        \
      for (int kk_ = 0; kk_ < 2; ++kk_)                                        \
        acc[(IO) + i_][(JO) + j_] = __builtin_amdgcn_mfma_f32_16x16x32_bf16(   \
            AF[i_][kk_], BF[j_][kk_], acc[(IO) + i_][(JO) + j_], 0, 0, 0);     \
    }                                                                          \
  }                                                                            \
  __builtin_amdgcn_s_setprio(0);

  stagePair(0, 0, 0); stagePair(0, 1, 0); stagePair(0, 2, 0); stagePair(0, 3, 0);
  stagePair(1, 0, 1); stagePair(1, 1, 1);
  WAIT_VM(6);
  BAR();
  readAF(afA, ldsBase, 0);
  readBF(bfA, ldsBase, 0);

  for (int t = 0; t < KT - 2; ++t) {
    const int c = t & 1;
    char* baseC = ldsBase + c * 65536;
    char* baseN = ldsBase + (c ^ 1) * 65536;
    readBF(bfB, baseC, 32);
    stagePair(c ^ 1, 2, t + 1);
    WAIT_VM(6); BAR();
    WAIT_LGKM(4); SCHEDB();
    MFMA16(afA, bfA, 0, 0);
    BAR();
    readAF(afB, baseC, 64);
    stagePair(c ^ 1, 3, t + 1);
    BAR();
    WAIT_LGKM(8); SCHEDB();
    MFMA16(afA, bfB, 0, 2);
    BAR();
    stagePair(c, 0, t + 2);
    WAIT_VM(4); BAR();
    WAIT_LGKM(0); SCHEDB();
    MFMA16(afB, bfA, 4, 0);
    BAR();
    readAF(afA, baseN, 0);
    readBF(bfA, baseN, 0);
    stagePair(c, 1, t + 2);
    WAIT_VM(8); BAR();
    WAIT_LGKM(12); SCHEDB();
    MFMA16(afB, bfB, 4, 2);
    BAR();
  }
  {
    const int t = KT - 2;
    const int c = t & 1;
    char* baseC = ldsBase + c * 65536;
    char* baseN = ldsBase + (c ^ 1) * 65536;
    readBF(bfB, baseC, 32);
    stagePair(c ^ 1, 2, t + 1);
    WAIT_VM(6); BAR();
    WAIT_LGKM(4); SCHEDB();
    MFMA16(afA, bfA, 0, 0);
    BAR();
    readAF(afB, baseC, 64);
    stagePair(c ^ 1, 3, t + 1);
    BAR();
    WAIT_LGKM(8); SCHEDB();
    MFMA16(afA, bfB, 0, 2);
    BAR();
    WAIT_VM(2); BAR();
    WAIT_LGKM(0); SCHEDB();
    MFMA16(afB, bfA, 4, 0);
    BAR();
    readAF(afA, baseN, 0);
    readBF(bfA, baseN, 0);
    WAIT_VM(4); BAR();
    WAIT_LGKM(12); SCHEDB();
    MFMA16(afB, bfB, 4, 2);
    BAR();
  }
  {
    const int t = KT - 1;
    char* baseC = ldsBase + (t & 1) * 65536;
    readBF(bfB, baseC, 32);
    WAIT_VM(0); BAR();
    WAIT_LGKM(4); SCHEDB();
    MFMA16(afA, bfA, 0, 0);
    BAR();
    readAF(afB, baseC, 64);
    BAR();
    WAIT_LGKM(8); SCHEDB();
    MFMA16(afA, bfB, 0, 2);
    BAR();
    WAIT_LGKM(0); SCHEDB();
    MFMA16(afB, bfA, 4, 0);
    MFMA16(afB, bfB, 4, 2);
  }
#undef MFMA16

  #pragma unroll
  for (int fi = 0; fi < 8; ++fi) {
    const int row = bm * 256 + wm * 128 + fi * 16 + q4 * 4;
    #pragma unroll
    for (int fj = 0; fj < 4; ++fj) {
      const int col = bn * 256 + wn * 64 + fj * 16 + r16;
      if constexpr (OUT_BF16) {
        unsigned short* C = (unsigned short*)Cout;
        #pragma unroll
        for (int rr = 0; rr < 4; ++rr)
          C[(size_t)(row + rr) * N + col] = f2b(acc[fi][fj][rr]);
      } else {
        float* C = (float*)Cout + (size_t)blockIdx.y * partStride;
        #pragma unroll
        for (int rr = 0; rr < 4; ++rr)
          C[(size_t)(row + rr) * N + col] = acc[fi][fj][rr];
      }
    }
  }
}

// ---------------- split-K reduce: out = p0 + p1 (f32) ----------------------
__global__ __launch_bounds__(256)
void k_add(const f32x4* __restrict__ a, const f32x4* __restrict__ b,
           f32x4* __restrict__ o, int n4) {
  int i = blockIdx.x * 256 + threadIdx.x;
  const int stride = gridDim.x * 256;
  for (; i < n4; i += stride) o[i] = a[i] + b[i];
}

// ---------------- RoPE on Q: qkv[t][h*128+d] -> Qr[h][t][d] ----------------
__global__ __launch_bounds__(256)
void k_rope_q(const unsigned short* __restrict__ qkv,
              const float* __restrict__ fc, const float* __restrict__ fs,
              unsigned short* __restrict__ Qr) {
  int idx = blockIdx.x * 256 + threadIdx.x;   // T*HQ*64
  int t   = idx >> 11;
  int rem = idx & 2047;
  int h   = rem >> 6;
  int d0  = (rem & 63) << 1;
  size_t qoff = (size_t)t * NQKV_ + h * HD_ + d0;
  u16x2 xv = *reinterpret_cast<const u16x2*>(&qkv[qoff]);
  float x0 = b2f(xv.x), x1 = b2f(xv.y);
  float c0 = fc[t * HD_ + d0], c1 = fc[t * HD_ + d0 + 1];
  float s0 = fs[t * HD_ + d0], s1 = fs[t * HD_ + d0 + 1];
  u16x2 o;
  o.x = f2b(x0 * c0 - x1 * s0);
  o.y = f2b(x1 * c1 + x0 * s1);
  *reinterpret_cast<u16x2*>(&Qr[((size_t)h * T_ + t) * HD_ + d0]) = o;
}

// ---------------- RoPE on K + scatter into Kall[hk][sp+t][d] ---------------
__global__ __launch_bounds__(256)
void k_rope_k(const unsigned short* __restrict__ qkv,
              const float* __restrict__ fc, const float* __restrict__ fs,
              unsigned short* __restrict__ Kall, const int* __restrict__ ipos) {
  int idx = blockIdx.x * 256 + threadIdx.x;   // T*HKV*64
  int t   = idx >> 9;
  int rem = idx & 511;
  int hk  = rem >> 6;
  int d0  = (rem & 63) << 1;
  int sp  = ipos[0];
  size_t qoff = (size_t)t * NQKV_ + HQ_ * HD_ + hk * HD_ + d0;
  u16x2 xv = *reinterpret_cast<const u16x2*>(&qkv[qoff]);
  float x0 = b2f(xv.x), x1 = b2f(xv.y);
  float c0 = fc[t * HD_ + d0], c1 = fc[t * HD_ + d0 + 1];
  float s0 = fs[t * HD_ + d0], s1 = fs[t * HD_ + d0 + 1];
  unsigned short o0 = f2b(x0 * c0 - x1 * s0);
  unsigned short o1 = f2b(x1 * c1 + x0 * s1);
  size_t ooff = ((size_t)hk * S_ + sp + t) * HD_ + d0;
  Kall[ooff] = o0; Kall[ooff + 1] = o1;
}

// ---------------- cache prefix (s < sp) into Kall / VT (grid-stride) -------
__global__ __launch_bounds__(256)
void k_prefix(const float* __restrict__ kc, const float* __restrict__ vc,
              unsigned short* __restrict__ Kall, unsigned short* __restrict__ VT,
              const int* __restrict__ ipos) {
  int sp = ipos[0];
  int total = sp * HKV_ * HD_;
  for (int idx = blockIdx.x * 256 + threadIdx.x; idx < total;
       idx += gridDim.x * 256) {
    int s   = idx >> 10;
    int rem = idx & 1023;
    int hk  = rem >> 7;
    int d   = rem & 127;
    Kall[((size_t)hk * S_ + s) * HD_ + d] = f2b(kc[((size_t)s * HKV_ + hk) * HD_ + d]);
    VT[((size_t)hk * HD_ + d) * S_ + s]   = f2b(vc[((size_t)s * HKV_ + hk) * HD_ + d]);
  }
}

// ---------------- V transpose: qkv v-section -> VT[hk][d][sp+t] ------------
__global__ __launch_bounds__(256)
void k_vt(const unsigned short* __restrict__ qkv,
          unsigned short* __restrict__ VT, const int* __restrict__ ipos) {
  int hk = blockIdx.x >> 5;     // 0..7
  int tt = blockIdx.x & 31;     // 0..31 (tiles of 64 t)
  int sp = ipos[0];
  __shared__ unsigned short lds[64][136];
  int tid = threadIdx.x;
  #pragma unroll
  for (int p = 0; p < 4; ++p) {
    int e   = p * 256 + tid;            // 0..1023
    int tr  = e >> 4;                   // 0..63
    int col = (e & 15) << 3;            // 0..120
    *reinterpret_cast<s16x8*>(&lds[tr][col]) =
        *reinterpret_cast<const s16x8*>(&qkv[(size_t)(tt * 64 + tr) * NQKV_ + (HQ_ + HKV_) * HD_ + hk * HD_ + col]);
  }
  __syncthreads();
  #pragma unroll
  for (int p = 0; p < 32; ++p) {
    int e = p * 256 + tid;              // 0..8191
    int d = e >> 6;                     // 0..127
    int t = e & 63;
    VT[((size_t)hk * HD_ + d) * S_ + sp + tt * 64 + t] = lds[t][d];
  }
}

// ---------------- flash attention v3 ---------------------------------------
// gld_lds staging with involution XOR swizzle (T2, rule#21), double-buffered
// K/V (64 KiB), counted vmcnt(8) prefetch (T3), LPT block order (longest qt
// first), hk = bid&7 for XCD L2 affinity. Swapped QK^T, in-register softmax.
// K buf c: byte(row,slot16) = c*16384 + row*256 + ((slot^(row&7))<<4)
// V buf c: byte(d,slot8)    = 32768 + c*16384 + d*128 + ((slot^(d&7))<<4)
__global__ __launch_bounds__(256, 2)
void k_attn(const unsigned short* __restrict__ Qr,
            const unsigned short* __restrict__ Kall,
            const unsigned short* __restrict__ VT,
            unsigned short* __restrict__ Y,
            const int* __restrict__ ipos) {
  constexpr int QB = 64, KB = 64;
  __shared__ char lds[65536];
  const int bid  = blockIdx.x;
  const int hk   = bid & 7;
  const int j2   = bid >> 3;                  // 0..127
  const int h    = hk * 4 + (j2 & 3);
  const int qt   = 31 - (j2 >> 2);            // LPT: longest first
  const int tid  = threadIdx.x, lane = tid & 63, wave = tid >> 6;
  const int r16  = lane & 15, q4 = lane >> 4;
  const int vx   = r16 & 7;                   // row-XOR for all LDS reads
  const float NEG_INF = -__builtin_inff();
  const float MINIT   = -1.0e30f;

  const int sp = ipos[0];
  const int qbase = qt * QB + wave * 16;
  const unsigned short* Kbase = Kall + (size_t)hk * S_ * HD_;
  const unsigned short* Vbase = VT + (size_t)hk * HD_ * S_;

  // Q fragments (4 vmem loads), then drain vmcnt so the stage ledger is exact
  s16x8 qf[4];
  const unsigned short* qp = Qr + ((size_t)h * T_ + qbase + r16) * HD_;
  #pragma unroll
  for (int ki = 0; ki < 4; ++ki)
    qf[ki] = *reinterpret_cast<const s16x8*>(qp + ki * 32 + q4 * 8);
  SCHEDB(); WAIT_VM(0); SCHEDB();

  auto stage = [&](int c, int jt) {           // 8 gld_lds per thread
    #pragma unroll
    for (int p = 0; p < 4; ++p) {
      int e  = p * 256 + tid;                 // 0..1023
      int kr = e >> 4;                        // K row 0..63
      int ks = (e & 15) ^ (kr & 7);           // pre-swizzled source slot
      gld_lds16(Kbase + (size_t)(jt * KB + kr) * HD_ + ks * 8,
                lds + c * 16384 + e * 16);
    }
    #pragma unroll
    for (int p = 0; p < 4; ++p) {
      int e  = p * 256 + tid;
      int vd = e >> 3;                        // V d-row 0..127
      int vs = (e & 7) ^ (vd & 7);
      gld_lds16(Vbase + (size_t)vd * S_ + jt * KB + vs * 8,
                lds + 32768 + c * 16384 + e * 16);
    }
  };

  f32x4 o[8] = {};
  float m = MINIT, l = 0.f;
  const int qpos = sp + qbase + r16;
  const int qpos_wave_max = sp + qbase + 15;
  int jmax = (sp + qt * QB + QB - 1) >> 6;
  if (jmax > S_ / KB - 1) jmax = S_ / KB - 1;
  const float scale2 = 0.12751744416312068f;  // 1/sqrt(128) * log2(e)

  stage(0, 0);                                // prologue: tile 0 in flight (8)

  for (int j = 0; j <= jmax; ++j) {
    const int c = j & 1;
    if (j < jmax) { stage(c ^ 1, j + 1); WAIT_VM(8); }  // j's 8 drained
    else         { WAIT_VM(0); }
    BAR();                                    // tile j published to all waves

    const bool active = (j * KB <= qpos_wave_max);
    if (active) {
      const char* kb = lds + c * 16384;
      const char* vb = lds + 32768 + c * 16384;
      // S^T = K Q^T : lane -> q=r16, kpos = j*64 + fn*16 + 4*q4 + reg
      f32x4 sfr[4];
      #pragma unroll
      for (int fn = 0; fn < 4; ++fn) {
        sfr[fn] = f32x4{0.f, 0.f, 0.f, 0.f};
        #pragma unroll
        for (int ki = 0; ki < 4; ++ki) {
          s16x8 kf = *(const s16x8*)(kb + (fn * 16 + r16) * 256 +
                                     (((ki * 4 + q4) ^ vx) << 4));
          sfr[fn] = __builtin_amdgcn_mfma_f32_16x16x32_bf16(kf, qf[ki], sfr[fn], 0, 0, 0);
        }
      }
      float p[16];
      const bool needMask = (j * KB + KB - 1) > (sp + qbase);   // wave-uniform
      if (needMask) {
        const int kbp = j * KB + q4 * 4;
        #pragma unroll
        for (int fn = 0; fn < 4; ++fn)
          #pragma unroll
          for (int r = 0; r < 4; ++r)
            p[fn * 4 + r] = (kbp + fn * 16 + r <= qpos) ? sfr[fn][r] * scale2 : NEG_INF;
      } else {
        #pragma unroll
        for (int fn = 0; fn < 4; ++fn)
          #pragma unroll
          for (int r = 0; r < 4; ++r)
            p[fn * 4 + r] = sfr[fn][r] * scale2;
      }
      float pmax = p[0];
      #pragma unroll
      for (int i = 1; i < 16; ++i) pmax = fmaxf(pmax, p[i]);
      pmax = fmaxf(pmax, __shfl_xor(pmax, 16));
      pmax = fmaxf(pmax, __shfl_xor(pmax, 32));
      if (!__all(pmax <= m + 8.0f)) {                 // defer-max (log2 units)
        float mn = fmaxf(m, pmax);
        float alpha = exp2a(m - mn);
        m = mn; l *= alpha;
        #pragma unroll
        for (int r = 0; r < 4; ++r) {
          float aq = __shfl(alpha, q4 * 4 + r);
          #pragma unroll
          for (int db = 0; db < 8; ++db) o[db][r] *= aq;
        }
      }
      float rs = 0.f;
      #pragma unroll
      for (int i = 0; i < 16; ++i) { p[i] = exp2a(p[i] - m); rs += p[i]; }
      rs += __shfl_xor(rs, 16); rs += __shfl_xor(rs, 32);
      l += rs;
      s16x8 pf[2];
      #pragma unroll
      for (int w = 0; w < 2; ++w)
        #pragma unroll
        for (int i = 0; i < 8; ++i)
          pf[w][i] = (short)f2b(p[w * 8 + i]);
      // PV: V-frag slots match pf's k-interleave; swizzled b64 pairs
      const int voff = (q4 & 1) * 8;
      const int sbase = q4 >> 1;
      #pragma unroll
      for (int w = 0; w < 2; ++w) {
        #pragma unroll
        for (int db = 0; db < 8; ++db) {
          const char* vr = vb + (db * 16 + r16) * 128 + voff;
          s16x4 va = *(const s16x4*)(vr + (((w * 4 + sbase) ^ vx) << 4));
          s16x4 vb2 = *(const s16x4*)(vr + (((w * 4 + 2 + sbase) ^ vx) << 4));
          s16x8 vf = __builtin_shufflevector(va, vb2, 0, 1, 2, 3, 4, 5, 6, 7);
          o[db] = __builtin_amdgcn_mfma_f32_16x16x32_bf16(pf[w], vf, o[db], 0, 0, 0);
        }
      }
    }
    BAR();   // all waves done reading buf c -> next stage may overwrite c^1..c
  }

  float rcpl = 1.0f / l;
  float rlq[4];
  #pragma unroll
  for (int r = 0; r < 4; ++r) rlq[r] = __shfl(rcpl, q4 * 4 + r);
  #pragma unroll
  for (int db = 0; db < 8; ++db)
    #pragma unroll
    for (int r = 0; r < 4; ++r) {
      int t = qt * QB + wave * 16 + q4 * 4 + r;
      int d = db * 16 + r16;
      Y[(size_t)t * (HQ_ * HD_) + h * HD_ + d] = f2b(o[db][r] * rlq[r]);
    }
}

// ---------------------------------------------------------------------------
extern "C" void kernel_launch(void* const* d_in, const int* in_sizes, int n_in,
                              void* d_out, int out_size, void* d_ws, size_t ws_size,
                              hipStream_t stream) {
  const float* x  = (const float*)d_in[0];
  const float* wq = (const float*)d_in[1];
  const float* wk = (const float*)d_in[2];
  const float* wv = (const float*)d_in[3];
  const float* wo = (const float*)d_in[4];
  const float* fc = (const float*)d_in[5];
  const float* fs = (const float*)d_in[6];
  const float* kc = (const float*)d_in[7];
  const float* vc = (const float*)d_in[8];
  const int* ipos = (const int*)d_in[9];

  char* ws = (char*)d_ws;
  unsigned short* xb   = (unsigned short*)(ws);                 // [0, 12.58 MB)
  unsigned short* wqkv = (unsigned short*)(ws + 12582912);      // [12.58, 50.33)
  unsigned short* qkv  = (unsigned short*)(ws + 50331648);      // [50.33, 75.50) (later y)
  unsigned short* Qr   = (unsigned short*)(ws + 75497472);      // [75.50, 92.27)
  unsigned short* Kall = (unsigned short*)(ws + 92274688);      // [92.27, 100.66)
  unsigned short* VT   = (unsigned short*)(ws + 100663296);     // [100.66, 109.05)
  unsigned short* wo_b = (unsigned short*)(ws);                 // reuse region 0 after QKV GEMM
  unsigned short* y    = qkv;                                   // reuse after rope/vt

  // split-K partials: z=0 dead-wqkv [12.58, 37.75); z=1 dead Qr+Kall [75.50, 100.66)
  float* part0 = (float*)(ws + 12582912);
  float* part1 = (float*)(ws + 75497472);
  const int partStrideElems = (75497472 - 12582912) / 4;        // 15728640

  // converts: x, wq, wk, wv -> bf16
  k_cvt<<<6144, 256, 0, stream>>>(x, xb, 6291456 / 4);
  k_cvt<<<12288, 256, 0, stream>>>(wq, wqkv, 12582912 / 4);
  k_cvt<<<3072, 256, 0, stream>>>(wk, wqkv + 12582912, 3145728 / 4);
  k_cvt<<<3072, 256, 0, stream>>>(wv, wqkv + 15728640, 3145728 / 4);

  // fused QKV projection: qkv[2048][6144] = xb @ wqkv^T   (grid 8x24=192)
  k_gemm256<true><<<192, 512, 0, stream>>>(xb, wqkv, qkv, NQKV_, DIM_, 48, 24, 24, 0, 0);

  // wo -> bf16 (region 0 dead now)
  k_cvt<<<12288, 256, 0, stream>>>(wo, wo_b, 12582912 / 4);

  // RoPE + scatter + V transpose
  k_rope_q<<<16384, 256, 0, stream>>>(qkv, fc, fs, Qr);
  k_rope_k<<<4096, 256, 0, stream>>>(qkv, fc, fs, Kall, ipos);
  k_prefix<<<2048, 256, 0, stream>>>(kc, vc, Kall, VT, ipos);
  k_vt<<<256, 256, 0, stream>>>(qkv, VT, ipos);

  // attention -> y[2048][4096] (bf16)
  k_attn<<<1024, 256, 0, stream>>>(Qr, Kall, VT, y, ipos);

  // output projection, split-K=2: part[z] = y @ wo_b^T (K half each)
  k_gemm256<false><<<dim3(96, 2), 512, 0, stream>>>(y, wo_b, part0, DIM_, HQ_ * HD_,
                                                    32, 12, 12, 2048, partStrideElems);
  // reduce: out = part0 + part1
  k_add<<<1024, 256, 0, stream>>>((const f32x4*)part0, (const f32x4*)part1,
                                  (f32x4*)d_out, 6291456 / 4);
}

// Round 8
// 273.881 us; speedup vs baseline: 1.5477x; 1.0489x over previous
//
#include <hip/hip_runtime.h>
#include <hip/hip_bf16.h>
#include <stdint.h>

typedef float f32x4 __attribute__((ext_vector_type(4)));
typedef short s16x8 __attribute__((ext_vector_type(8)));
typedef short s16x4 __attribute__((ext_vector_type(4)));
typedef unsigned short u16x2 __attribute__((ext_vector_type(2)));
typedef unsigned short u16x4 __attribute__((ext_vector_type(4)));

#define AS1 __attribute__((address_space(1)))
#define AS3 __attribute__((address_space(3)))

static constexpr int T_    = 2048;
static constexpr int DIM_  = 3072;
static constexpr int HQ_   = 32;
static constexpr int HKV_  = 8;
static constexpr int HD_   = 128;
static constexpr int S_    = 4096;
static constexpr int NQKV_ = HQ_ * HD_ + 2 * HKV_ * HD_;   // 6144

__device__ __forceinline__ unsigned short f2b(float f) {
  return __builtin_bit_cast(unsigned short, __float2bfloat16(f));
}
__device__ __forceinline__ float b2f(unsigned short u) {
  return __bfloat162float(__builtin_bit_cast(__hip_bfloat16, u));
}
__device__ __forceinline__ float exp2a(float x) {      // exact v_exp_f32: 2^x
  float r; asm("v_exp_f32 %0, %1" : "=v"(r) : "v"(x)); return r;
}

__device__ __forceinline__ void gld_lds16(const void* g, void* l) {
  __builtin_amdgcn_global_load_lds((AS1 unsigned int*)(uintptr_t)g,
                                   (AS3 unsigned int*)l, 16, 0, 0);
}

#define FENCE() asm volatile("" ::: "memory")
#define BAR()   do { FENCE(); __builtin_amdgcn_s_barrier(); FENCE(); } while (0)
#define WAIT_VM(n)   asm volatile("s_waitcnt vmcnt(" #n ")" ::: "memory")
#define WAIT_LGKM(n) asm volatile("s_waitcnt lgkmcnt(" #n ")" ::: "memory")
#define SCHEDB()     __builtin_amdgcn_sched_barrier(0)

// ---------------- f32 -> bf16 convert ----------------
__global__ __launch_bounds__(256)
void k_cvt(const float* __restrict__ src, unsigned short* __restrict__ dst, int n4) {
  int i = blockIdx.x * 256 + threadIdx.x;
  if (i >= n4) return;
  float4 v = reinterpret_cast<const float4*>(src)[i];
  u16x4 o;
  o.x = f2b(v.x); o.y = f2b(v.y); o.z = f2b(v.z); o.w = f2b(v.w);
  reinterpret_cast<u16x4*>(dst)[i] = o;
}

// merged wq/wk/wv convert into contiguous wqkv (saves 2 launches)
__global__ __launch_bounds__(256)
void k_cvtW(const float* __restrict__ wq, const float* __restrict__ wk,
            const float* __restrict__ wv, unsigned short* __restrict__ dst) {
  int idx = blockIdx.x * 256 + threadIdx.x;            // float4 units
  if (idx >= 4718592) return;
  const float* src; int s;
  if (idx < 3145728)      { src = wq; s = idx; }
  else if (idx < 3932160) { src = wk; s = idx - 3145728; }
  else                    { src = wv; s = idx - 3932160; }
  float4 v = reinterpret_cast<const float4*>(src)[s];
  u16x4 o;
  o.x = f2b(v.x); o.y = f2b(v.y); o.z = f2b(v.z); o.w = f2b(v.w);
  reinterpret_cast<u16x4*>(dst)[idx] = o;
}

// ---------------- 128x192 8-wave NT GEMM, 2 blocks/CU -----------------------
// C[M][N] = A[M][K] * B[N][K]^T. 512 thr = 8 waves (2M x 4N), wave tile 64x48,
// acc[4][3]. LDS 2 x (A 128x64 + B 192x64) bf16 = 80 KiB -> 2 blocks/CU
// (163840 B exactly): co-resident block hides barrier/vmcnt stalls.
// 3 phases/K-tile: read {af(8)+bf0(2) / bf1(2) / bf2(2)} (read-once, 14 b128),
// stage next tile spread 2A+2B+1B, lgkmcnt(0)+SCHEDB+setprio per phase,
// vmcnt(0) only at tile end. XOR involution swizzle (0 conflicts).
template<bool OUT_BF16>
__global__ __launch_bounds__(512, 4)
void k_gemm192(const unsigned short* __restrict__ A,
               const unsigned short* __restrict__ B,
               void* __restrict__ Cout, int N, int K, int KT,
               int nbn, int xcdq) {
  __shared__ char lds[81920];                          // 2 x 40960
  const int bid = blockIdx.x;
  const int swz = (bid & 7) * xcdq + (bid >> 3);       // bijective: nwg % 8 == 0
  const int bm  = swz / nbn, bn = swz % nbn;
  const int tid = threadIdx.x, lane = tid & 63, wid = tid >> 6;
  const int wm  = wid >> 2, wn = wid & 3;              // 2 x 4
  const int r16 = lane & 15, q4 = lane >> 4;

  const unsigned short* Ag = A + (size_t)(bm * 128) * K;
  const unsigned short* Bg = B + (size_t)(bn * 192) * K;

  const int srow = tid >> 3;                            // 0..63
  const int scol = ((tid & 7) ^ (srow & 7)) * 8;        // pre-swizzled src col

  f32x4 acc[4][3] = {};
  s16x8 af[4][2];

  auto stageA = [&](int c, int r, int t) {              // r in {0,1}
    gld_lds16(Ag + (size_t)(r * 64 + srow) * K + t * 64 + scol,
              lds + c * 40960 + r * 8192 + tid * 16);
  };
  auto stageB = [&](int c, int r, int t) {              // r in {0,1,2}
    gld_lds16(Bg + (size_t)(r * 64 + srow) * K + t * 64 + scol,
              lds + c * 40960 + 16384 + r * 8192 + tid * 16);
  };
  auto readA = [&](int c) {
    #pragma unroll
    for (int i = 0; i < 4; ++i) {
      const int arow = wm * 64 + i * 16 + r16;
      #pragma unroll
      for (int kk = 0; kk < 2; ++kk)
        af[i][kk] = *(const s16x8*)(lds + c * 40960 + arow * 128 +
                                    (((kk * 4 + q4) ^ (arow & 7)) << 4));
    }
  };
  auto readB = [&](s16x8 (&dst)[2], int c, int j) {
    const int brow = wn * 48 + j * 16 + r16;
    #pragma unroll
    for (int kk = 0; kk < 2; ++kk)
      dst[kk] = *(const s16x8*)(lds + c * 40960 + 16384 + brow * 128 +
                                (((kk * 4 + q4) ^ (brow & 7)) << 4));
  };

#define MFMA8(BF, J)                                                           \
  __builtin_amdgcn_s_setprio(1);                                               \
  _Pragma("unroll")                                                            \
  for (int i_ = 0; i_ < 4; ++i_) {                                             \
    _Pragma("unroll")                                                          \
    for (int kk_ = 0; kk_ < 2; ++kk_)                                          \
      acc[i_][J] = __builtin_amdgcn_mfma_f32_16x16x32_bf16(                    \
          af[i_][kk_], BF[kk_], acc[i_][J], 0, 0, 0);                          \
  }                                                                            \
  __builtin_amdgcn_s_setprio(0);

  // prologue: stage tile 0 into buf 0, drain, publish
  stageA(0, 0, 0); stageA(0, 1, 0);
  stageB(0, 0, 0); stageB(0, 1, 0); stageB(0, 2, 0);
  WAIT_VM(0);
  BAR();

  for (int t = 0; t < KT; ++t) {
    const int c = t & 1;
    const bool hn = (t + 1 < KT);
    // P0: af + bf0
    {
      s16x8 bfc[2];
      readA(c); readB(bfc, c, 0);
      if (hn) { stageA(c ^ 1, 0, t + 1); stageA(c ^ 1, 1, t + 1); }
      BAR();
      WAIT_LGKM(0); SCHEDB();
      MFMA8(bfc, 0);
      BAR();
    }
    // P1: bf1
    {
      s16x8 bfc[2];
      readB(bfc, c, 1);
      if (hn) { stageB(c ^ 1, 0, t + 1); stageB(c ^ 1, 1, t + 1); }
      BAR();
      WAIT_LGKM(0); SCHEDB();
      MFMA8(bfc, 1);
      BAR();
    }
    // P2: bf2, then publish next tile
    {
      s16x8 bfc[2];
      readB(bfc, c, 2);
      if (hn) stageB(c ^ 1, 2, t + 1);
      BAR();
      WAIT_LGKM(0); SCHEDB();
      MFMA8(bfc, 2);
      if (hn) { WAIT_VM(0); }
      BAR();
    }
  }
#undef MFMA8

  // epilogue: acc[i][j] -> row bm*128 + wm*64 + i*16, col bn*192 + wn*48 + j*16
  #pragma unroll
  for (int i = 0; i < 4; ++i) {
    const int row = bm * 128 + wm * 64 + i * 16 + q4 * 4;
    #pragma unroll
    for (int j = 0; j < 3; ++j) {
      const int col = bn * 192 + wn * 48 + j * 16 + r16;
      if constexpr (OUT_BF16) {
        unsigned short* C = (unsigned short*)Cout;
        #pragma unroll
        for (int rr = 0; rr < 4; ++rr)
          C[(size_t)(row + rr) * N + col] = f2b(acc[i][j][rr]);
      } else {
        float* C = (float*)Cout;
        #pragma unroll
        for (int rr = 0; rr < 4; ++rr)
          C[(size_t)(row + rr) * N + col] = acc[i][j][rr];
      }
    }
  }
}

// ---------------- RoPE on Q: qkv[t][h*128+d] -> Qr[h][t][d] ----------------
__global__ __launch_bounds__(256)
void k_rope_q(const unsigned short* __restrict__ qkv,
              const float* __restrict__ fc, const float* __restrict__ fs,
              unsigned short* __restrict__ Qr) {
  int idx = blockIdx.x * 256 + threadIdx.x;   // T*HQ*64
  int t   = idx >> 11;
  int rem = idx & 2047;
  int h   = rem >> 6;
  int d0  = (rem & 63) << 1;
  size_t qoff = (size_t)t * NQKV_ + h * HD_ + d0;
  u16x2 xv = *reinterpret_cast<const u16x2*>(&qkv[qoff]);
  float x0 = b2f(xv.x), x1 = b2f(xv.y);
  float c0 = fc[t * HD_ + d0], c1 = fc[t * HD_ + d0 + 1];
  float s0 = fs[t * HD_ + d0], s1 = fs[t * HD_ + d0 + 1];
  u16x2 o;
  o.x = f2b(x0 * c0 - x1 * s0);
  o.y = f2b(x1 * c1 + x0 * s1);
  *reinterpret_cast<u16x2*>(&Qr[((size_t)h * T_ + t) * HD_ + d0]) = o;
}

// ---------------- RoPE on K + scatter into Kall[hk][sp+t][d] ---------------
__global__ __launch_bounds__(256)
void k_rope_k(const unsigned short* __restrict__ qkv,
              const float* __restrict__ fc, const float* __restrict__ fs,
              unsigned short* __restrict__ Kall, const int* __restrict__ ipos) {
  int idx = blockIdx.x * 256 + threadIdx.x;   // T*HKV*64
  int t   = idx >> 9;
  int rem = idx & 511;
  int hk  = rem >> 6;
  int d0  = (rem & 63) << 1;
  int sp  = ipos[0];
  size_t qoff = (size_t)t * NQKV_ + HQ_ * HD_ + hk * HD_ + d0;
  u16x2 xv = *reinterpret_cast<const u16x2*>(&qkv[qoff]);
  float x0 = b2f(xv.x), x1 = b2f(xv.y);
  float c0 = fc[t * HD_ + d0], c1 = fc[t * HD_ + d0 + 1];
  float s0 = fs[t * HD_ + d0], s1 = fs[t * HD_ + d0 + 1];
  unsigned short o0 = f2b(x0 * c0 - x1 * s0);
  unsigned short o1 = f2b(x1 * c1 + x0 * s1);
  size_t ooff = ((size_t)hk * S_ + sp + t) * HD_ + d0;
  Kall[ooff] = o0; Kall[ooff + 1] = o1;
}

// ---------------- cache prefix (s < sp) into Kall / VT (grid-stride) -------
__global__ __launch_bounds__(256)
void k_prefix(const float* __restrict__ kc, const float* __restrict__ vc,
              unsigned short* __restrict__ Kall, unsigned short* __restrict__ VT,
              const int* __restrict__ ipos) {
  int sp = ipos[0];
  int total = sp * HKV_ * HD_;
  for (int idx = blockIdx.x * 256 + threadIdx.x; idx < total;
       idx += gridDim.x * 256) {
    int s   = idx >> 10;
    int rem = idx & 1023;
    int hk  = rem >> 7;
    int d   = rem & 127;
    Kall[((size_t)hk * S_ + s) * HD_ + d] = f2b(kc[((size_t)s * HKV_ + hk) * HD_ + d]);
    VT[((size_t)hk * HD_ + d) * S_ + s]   = f2b(vc[((size_t)s * HKV_ + hk) * HD_ + d]);
  }
}

// ---------------- V transpose: qkv v-section -> VT[hk][d][sp+t] ------------
__global__ __launch_bounds__(256)
void k_vt(const unsigned short* __restrict__ qkv,
          unsigned short* __restrict__ VT, const int* __restrict__ ipos) {
  int hk = blockIdx.x >> 5;     // 0..7
  int tt = blockIdx.x & 31;     // 0..31 (tiles of 64 t)
  int sp = ipos[0];
  __shared__ unsigned short lds[64][136];
  int tid = threadIdx.x;
  #pragma unroll
  for (int p = 0; p < 4; ++p) {
    int e   = p * 256 + tid;            // 0..1023
    int tr  = e >> 4;                   // 0..63
    int col = (e & 15) << 3;            // 0..120
    *reinterpret_cast<s16x8*>(&lds[tr][col]) =
        *reinterpret_cast<const s16x8*>(&qkv[(size_t)(tt * 64 + tr) * NQKV_ + (HQ_ + HKV_) * HD_ + hk * HD_ + col]);
  }
  __syncthreads();
  #pragma unroll
  for (int p = 0; p < 32; ++p) {
    int e = p * 256 + tid;              // 0..8191
    int d = e >> 6;                     // 0..127
    int t = e & 63;
    VT[((size_t)hk * HD_ + d) * S_ + sp + tt * 64 + t] = lds[t][d];
  }
}

// ---------------- flash attention v3 (unchanged, verified round 7) ----------
__global__ __launch_bounds__(256, 2)
void k_attn(const unsigned short* __restrict__ Qr,
            const unsigned short* __restrict__ Kall,
            const unsigned short* __restrict__ VT,
            unsigned short* __restrict__ Y,
            const int* __restrict__ ipos) {
  constexpr int QB = 64, KB = 64;
  __shared__ char lds[65536];
  const int bid  = blockIdx.x;
  const int hk   = bid & 7;
  const int j2   = bid >> 3;                  // 0..127
  const int h    = hk * 4 + (j2 & 3);
  const int qt   = 31 - (j2 >> 2);            // LPT: longest first
  const int tid  = threadIdx.x, lane = tid & 63, wave = tid >> 6;
  const int r16  = lane & 15, q4 = lane >> 4;
  const int vx   = r16 & 7;                   // row-XOR for all LDS reads
  const float NEG_INF = -__builtin_inff();
  const float MINIT   = -1.0e30f;

  const int sp = ipos[0];
  const int qbase = qt * QB + wave * 16;
  const unsigned short* Kbase = Kall + (size_t)hk * S_ * HD_;
  const unsigned short* Vbase = VT + (size_t)hk * HD_ * S_;

  s16x8 qf[4];
  const unsigned short* qp = Qr + ((size_t)h * T_ + qbase + r16) * HD_;
  #pragma unroll
  for (int ki = 0; ki < 4; ++ki)
    qf[ki] = *reinterpret_cast<const s16x8*>(qp + ki * 32 + q4 * 8);
  SCHEDB(); WAIT_VM(0); SCHEDB();

  auto stage = [&](int c, int jt) {           // 8 gld_lds per thread
    #pragma unroll
    for (int p = 0; p < 4; ++p) {
      int e  = p * 256 + tid;                 // 0..1023
      int kr = e >> 4;                        // K row 0..63
      int ks = (e & 15) ^ (kr & 7);           // pre-swizzled source slot
      gld_lds16(Kbase + (size_t)(jt * KB + kr) * HD_ + ks * 8,
                lds + c * 16384 + e * 16);
    }
    #pragma unroll
    for (int p = 0; p < 4; ++p) {
      int e  = p * 256 + tid;
      int vd = e >> 3;                        // V d-row 0..127
      int vs = (e & 7) ^ (vd & 7);
      gld_lds16(Vbase + (size_t)vd * S_ + jt * KB + vs * 8,
                lds + 32768 + c * 16384 + e * 16);
    }
  };

  f32x4 o[8] = {};
  float m = MINIT, l = 0.f;
  const int qpos = sp + qbase + r16;
  const int qpos_wave_max = sp + qbase + 15;
  int jmax = (sp + qt * QB + QB - 1) >> 6;
  if (jmax > S_ / KB - 1) jmax = S_ / KB - 1;
  const float scale2 = 0.12751744416312068f;  // 1/sqrt(128) * log2(e)

  stage(0, 0);                                // prologue: tile 0 in flight (8)

  for (int j = 0; j <= jmax; ++j) {
    const int c = j & 1;
    if (j < jmax) { stage(c ^ 1, j + 1); WAIT_VM(8); }  // j's 8 drained
    else         { WAIT_VM(0); }
    BAR();                                    // tile j published to all waves

    const bool active = (j * KB <= qpos_wave_max);
    if (active) {
      const char* kb = lds + c * 16384;
      const char* vb = lds + 32768 + c * 16384;
      f32x4 sfr[4];
      #pragma unroll
      for (int fn = 0; fn < 4; ++fn) {
        sfr[fn] = f32x4{0.f, 0.f, 0.f, 0.f};
        #pragma unroll
        for (int ki = 0; ki < 4; ++ki) {
          s16x8 kf = *(const s16x8*)(kb + (fn * 16 + r16) * 256 +
                                     (((ki * 4 + q4) ^ vx) << 4));
          sfr[fn] = __builtin_amdgcn_mfma_f32_16x16x32_bf16(kf, qf[ki], sfr[fn], 0, 0, 0);
        }
      }
      float p[16];
      const bool needMask = (j * KB + KB - 1) > (sp + qbase);   // wave-uniform
      if (needMask) {
        const int kbp = j * KB + q4 * 4;
        #pragma unroll
        for (int fn = 0; fn < 4; ++fn)
          #pragma unroll
          for (int r = 0; r < 4; ++r)
            p[fn * 4 + r] = (kbp + fn * 16 + r <= qpos) ? sfr[fn][r] * scale2 : NEG_INF;
      } else {
        #pragma unroll
        for (int fn = 0; fn < 4; ++fn)
          #pragma unroll
          for (int r = 0; r < 4; ++r)
            p[fn * 4 + r] = sfr[fn][r] * scale2;
      }
      float pmax = p[0];
      #pragma unroll
      for (int i = 1; i < 16; ++i) pmax = fmaxf(pmax, p[i]);
      pmax = fmaxf(pmax, __shfl_xor(pmax, 16));
      pmax = fmaxf(pmax, __shfl_xor(pmax, 32));
      if (!__all(pmax <= m + 8.0f)) {                 // defer-max (log2 units)
        float mn = fmaxf(m, pmax);
        float alpha = exp2a(m - mn);
        m = mn; l *= alpha;
        #pragma unroll
        for (int r = 0; r < 4; ++r) {
          float aq = __shfl(alpha, q4 * 4 + r);
          #pragma unroll
          for (int db = 0; db < 8; ++db) o[db][r] *= aq;
        }
      }
      float rs = 0.f;
      #pragma unroll
      for (int i = 0; i < 16; ++i) { p[i] = exp2a(p[i] - m); rs += p[i]; }
      rs += __shfl_xor(rs, 16); rs += __shfl_xor(rs, 32);
      l += rs;
      s16x8 pf[2];
      #pragma unroll
      for (int w = 0; w < 2; ++w)
        #pragma unroll
        for (int i = 0; i < 8; ++i)
          pf[w][i] = (short)f2b(p[w * 8 + i]);
      const int voff = (q4 & 1) * 8;
      const int sbase = q4 >> 1;
      #pragma unroll
      for (int w = 0; w < 2; ++w) {
        #pragma unroll
        for (int db = 0; db < 8; ++db) {
          const char* vr = vb + (db * 16 + r16) * 128 + voff;
          s16x4 va = *(const s16x4*)(vr + (((w * 4 + sbase) ^ vx) << 4));
          s16x4 vb2 = *(const s16x4*)(vr + (((w * 4 + 2 + sbase) ^ vx) << 4));
          s16x8 vf = __builtin_shufflevector(va, vb2, 0, 1, 2, 3, 4, 5, 6, 7);
          o[db] = __builtin_amdgcn_mfma_f32_16x16x32_bf16(pf[w], vf, o[db], 0, 0, 0);
        }
      }
    }
    BAR();   // all waves done reading buf c
  }

  float rcpl = 1.0f / l;
  float rlq[4];
  #pragma unroll
  for (int r = 0; r < 4; ++r) rlq[r] = __shfl(rcpl, q4 * 4 + r);
  #pragma unroll
  for (int db = 0; db < 8; ++db)
    #pragma unroll
    for (int r = 0; r < 4; ++r) {
      int t = qt * QB + wave * 16 + q4 * 4 + r;
      int d = db * 16 + r16;
      Y[(size_t)t * (HQ_ * HD_) + h * HD_ + d] = f2b(o[db][r] * rlq[r]);
    }
}

// ---------------------------------------------------------------------------
extern "C" void kernel_launch(void* const* d_in, const int* in_sizes, int n_in,
                              void* d_out, int out_size, void* d_ws, size_t ws_size,
                              hipStream_t stream) {
  const float* x  = (const float*)d_in[0];
  const float* wq = (const float*)d_in[1];
  const float* wk = (const float*)d_in[2];
  const float* wv = (const float*)d_in[3];
  const float* wo = (const float*)d_in[4];
  const float* fc = (const float*)d_in[5];
  const float* fs = (const float*)d_in[6];
  const float* kc = (const float*)d_in[7];
  const float* vc = (const float*)d_in[8];
  const int* ipos = (const int*)d_in[9];

  char* ws = (char*)d_ws;
  unsigned short* xb   = (unsigned short*)(ws);                 // [0, 12.58 MB)
  unsigned short* wqkv = (unsigned short*)(ws + 12582912);      // [12.58, 50.33)
  unsigned short* qkv  = (unsigned short*)(ws + 50331648);      // [50.33, 75.50) (later y)
  unsigned short* Qr   = (unsigned short*)(ws + 75497472);      // [75.50, 92.27)
  unsigned short* Kall = (unsigned short*)(ws + 92274688);      // [92.27, 100.66)
  unsigned short* VT   = (unsigned short*)(ws + 100663296);     // [100.66, 109.05)
  unsigned short* wo_b = (unsigned short*)(ws);                 // reuse region 0 after QKV GEMM
  unsigned short* y    = qkv;                                   // reuse after rope/vt

  // converts: x -> bf16; wq+wk+wv -> wqkv (merged)
  k_cvt<<<6144, 256, 0, stream>>>(x, xb, 6291456 / 4);
  k_cvtW<<<18432, 256, 0, stream>>>(wq, wk, wv, wqkv);

  // fused QKV projection: qkv[2048][6144] = xb @ wqkv^T
  // grid 16x32 = 512 blocks = 2 blocks/CU on all 256 CUs
  k_gemm192<true><<<512, 512, 0, stream>>>(xb, wqkv, qkv, NQKV_, DIM_, 48, 32, 64);

  // wo -> bf16 (region 0 dead now)
  k_cvt<<<12288, 256, 0, stream>>>(wo, wo_b, 12582912 / 4);

  // RoPE + scatter + V transpose
  k_rope_q<<<16384, 256, 0, stream>>>(qkv, fc, fs, Qr);
  k_rope_k<<<4096, 256, 0, stream>>>(qkv, fc, fs, Kall, ipos);
  k_prefix<<<2048, 256, 0, stream>>>(kc, vc, Kall, VT, ipos);
  k_vt<<<256, 256, 0, stream>>>(qkv, VT, ipos);

  // attention -> y[2048][4096] (bf16)
  k_attn<<<1024, 256, 0, stream>>>(Qr, Kall, VT, y, ipos);

  // output projection: out[2048][3072] = y @ wo_b^T, f32 direct (no split-K)
  // grid 16x16 = 256 blocks
  k_gemm192<false><<<256, 512, 0, stream>>>(y, wo_b, d_out, DIM_, HQ_ * HD_, 64, 16, 32);
}